// Round 1
// baseline (2226.694 us; speedup 1.0000x reference)
//
#include <hip/hip_runtime.h>

#define B_   8
#define L_   512
#define H_   768
#define NH_  12
#define DFF_ 3072
#define NL_  4
#define HD_  64
#define M_   4096

typedef __bf16 bf16x8 __attribute__((ext_vector_type(8)));
typedef float f32x4 __attribute__((ext_vector_type(4)));
typedef unsigned short u16x8 __attribute__((ext_vector_type(8)));

__device__ inline float bf2f(unsigned short u){
  union { unsigned int i; float f; } v; v.i = ((unsigned int)u) << 16; return v.f;
}
__device__ inline unsigned short f2bf(float f){
  union { float f; unsigned int i; } v; v.f = f;
  unsigned int x = v.i;
  return (unsigned short)((x + 0x7fffu + ((x >> 16) & 1u)) >> 16);
}

// ---------------- weight prep: transpose fp32 [R][C] -> bf16 [C][R] ----------------
// One fused kernel for all 4 layers x 6 matrices. 32x32 tiles, LDS transpose.
// Per-layer wT layout (elements): Wq^T@0, Wk^T@589824, Wv^T@1179648, Wo^T@1769472,
// W1^T@2359296 (3072x768), W2^T@4718592 (768x3072). Layer stride 7077888.
__global__ void k_prep_weights(const float* __restrict__ Wq, const float* __restrict__ Wk,
                               const float* __restrict__ Wv, const float* __restrict__ Wo,
                               const float* __restrict__ W1, const float* __restrict__ W2,
                               unsigned short* __restrict__ wTall){
  __shared__ float tile[32][33];
  int id = blockIdx.x;
  int layer = id / 6912;
  int r = id % 6912;
  unsigned short* wt = wTall + (size_t)layer * 7077888;
  const float* src; unsigned short* dst; int R, C, tr;
  if (r < 2304){
    int mat = r / 576; tr = r % 576; R = 768; C = 768;
    const float* s;
    if (mat == 0) s = Wq; else if (mat == 1) s = Wk; else if (mat == 2) s = Wv; else s = Wo;
    src = s + (size_t)layer * 589824;
    dst = wt + (size_t)mat * 589824;
  } else if (r < 4608){
    tr = r - 2304; R = 768; C = 3072;
    src = W1 + (size_t)layer * 2359296; dst = wt + 2359296;
  } else {
    tr = r - 4608; R = 3072; C = 768;
    src = W2 + (size_t)layer * 2359296; dst = wt + 4718592;
  }
  int tilesC = C >> 5;
  int r0 = (tr / tilesC) << 5, c0 = (tr % tilesC) << 5;
  int tx = threadIdx.x, ty = threadIdx.y; // (32,8)
  #pragma unroll
  for (int i = 0; i < 32; i += 8)
    tile[ty + i][tx] = src[(size_t)(r0 + ty + i) * C + c0 + tx];
  __syncthreads();
  #pragma unroll
  for (int j = 0; j < 32; j += 8)
    dst[(size_t)(c0 + ty + j) * R + r0 + tx] = f2bf(tile[tx][ty + j]);
}

// concat qkv bias per layer: [NL][2304]
__global__ void k_prep_bias(const float* __restrict__ bq, const float* __restrict__ bk,
                            const float* __restrict__ bv, float* __restrict__ out){
  int i = blockIdx.x * 256 + threadIdx.x; // 4*2304
  int layer = i / 2304, c = i % 2304;
  float v;
  if (c < 768) v = bq[layer * 768 + c];
  else if (c < 1536) v = bk[layer * 768 + c - 768];
  else v = bv[layer * 768 + c - 1536];
  out[i] = v;
}

// ---------------- embedding + LN ----------------
__global__ __launch_bounds__(256) void k_embed_ln(const int* __restrict__ ids, const int* __restrict__ tts,
                           const float* __restrict__ we, const float* __restrict__ pe,
                           const float* __restrict__ te, const float* __restrict__ g,
                           const float* __restrict__ b, float* __restrict__ x,
                           unsigned short* __restrict__ xb){
  int row = blockIdx.x;           // 4096
  int l = row & 511;
  int id = ids[row], tt = tts[row];
  int t = threadIdx.x;            // 256
  float v[3]; float s = 0.f, s2 = 0.f;
  #pragma unroll
  for (int i = 0; i < 3; i++){
    int c = t + i * 256;
    float val = we[(size_t)id * 768 + c] + pe[(size_t)l * 768 + c] + te[(size_t)tt * 768 + c];
    v[i] = val; s += val; s2 += val * val;
  }
  #pragma unroll
  for (int o = 32; o > 0; o >>= 1){ s += __shfl_down(s, o); s2 += __shfl_down(s2, o); }
  __shared__ float red[2][4];
  int wv = t >> 6;
  if ((t & 63) == 0){ red[0][wv] = s; red[1][wv] = s2; }
  __syncthreads();
  s = red[0][0] + red[0][1] + red[0][2] + red[0][3];
  s2 = red[1][0] + red[1][1] + red[1][2] + red[1][3];
  float mean = s * (1.f / 768.f);
  float var = s2 * (1.f / 768.f) - mean * mean;
  float rstd = rsqrtf(var + 1e-12f);
  #pragma unroll
  for (int i = 0; i < 3; i++){
    int c = t + i * 256;
    float nv = (v[i] - mean) * rstd * g[c] + b[c];
    x[(size_t)row * 768 + c] = nv;
    xb[(size_t)row * 768 + c] = f2bf(nv);
  }
}

// ---------------- residual add + LN (in-place on x) ----------------
__global__ __launch_bounds__(256) void k_add_ln(const float* __restrict__ xin, const float* __restrict__ y,
                         const float* __restrict__ g, const float* __restrict__ b,
                         float* __restrict__ x, unsigned short* __restrict__ xb){
  int row = blockIdx.x;
  int t = threadIdx.x;
  float v[3]; float s = 0.f, s2 = 0.f;
  #pragma unroll
  for (int i = 0; i < 3; i++){
    int c = t + i * 256;
    float val = xin[(size_t)row * 768 + c] + y[(size_t)row * 768 + c];
    v[i] = val; s += val; s2 += val * val;
  }
  #pragma unroll
  for (int o = 32; o > 0; o >>= 1){ s += __shfl_down(s, o); s2 += __shfl_down(s2, o); }
  __shared__ float red[2][4];
  int wv = t >> 6;
  if ((t & 63) == 0){ red[0][wv] = s; red[1][wv] = s2; }
  __syncthreads();
  s = red[0][0] + red[0][1] + red[0][2] + red[0][3];
  s2 = red[1][0] + red[1][1] + red[1][2] + red[1][3];
  float mean = s * (1.f / 768.f);
  float var = s2 * (1.f / 768.f) - mean * mean;
  float rstd = rsqrtf(var + 1e-12f);
  #pragma unroll
  for (int i = 0; i < 3; i++){
    int c = t + i * 256;
    float nv = (v[i] - mean) * rstd * g[c] + b[c];
    x[(size_t)row * 768 + c] = nv;
    xb[(size_t)row * 768 + c] = f2bf(nv);
  }
}

// ---------------- bf16 MFMA GEMM: C[M][N] = A[M][K] @ BT[N][K]^T + bias ----------------
// MODE 0: f32 out (+bias); MODE 1: bf16 out (+bias); MODE 2: bf16 gelu(out+bias)
template<int MODE>
__global__ __launch_bounds__(256) void k_gemm(const unsigned short* __restrict__ A,
                                              const unsigned short* __restrict__ BT,
                                              const float* __restrict__ bias,
                                              void* __restrict__ Cout,
                                              int M, int N, int K){
  __shared__ __attribute__((aligned(16))) unsigned short As[128 * 64];
  __shared__ __attribute__((aligned(16))) unsigned short Bs[128 * 64];
  int tid = threadIdx.x;
  int lane = tid & 63, wave = tid >> 6;
  int bm0 = blockIdx.y * 128, bn0 = blockIdx.x * 128;
  int wr = wave >> 1, wc = wave & 1;

  f32x4 acc[4][4];
  #pragma unroll
  for (int m = 0; m < 4; m++)
    #pragma unroll
    for (int n = 0; n < 4; n++)
      acc[m][n] = (f32x4){0.f, 0.f, 0.f, 0.f};

  const unsigned short* gaBase = A + (size_t)(bm0 + (lane >> 3)) * K + ((lane & 7) << 3);
  const unsigned short* gbBase = BT + (size_t)(bn0 + (lane >> 3)) * K + ((lane & 7) << 3);

  int nk = K >> 6;
  for (int t = 0; t < nk; t++){
    __syncthreads();
    const unsigned short* gA = gaBase + (t << 6);
    const unsigned short* gB = gbBase + (t << 6);
    #pragma unroll
    for (int i = 0; i < 4; i++){
      int ro = (wave * 4 + i) * 8;
      __builtin_amdgcn_global_load_lds(
        (const __attribute__((address_space(1))) void*)(gA + (size_t)ro * K),
        (__attribute__((address_space(3))) void*)(As + (wave * 4 + i) * 512), 16, 0, 0);
      __builtin_amdgcn_global_load_lds(
        (const __attribute__((address_space(1))) void*)(gB + (size_t)ro * K),
        (__attribute__((address_space(3))) void*)(Bs + (wave * 4 + i) * 512), 16, 0, 0);
    }
    __syncthreads();
    #pragma unroll
    for (int kk = 0; kk < 2; kk++){
      bf16x8 av[4], bv[4];
      #pragma unroll
      for (int m = 0; m < 4; m++)
        av[m] = *(const bf16x8*)(As + (wr * 64 + m * 16 + (lane & 15)) * 64 + kk * 32 + ((lane >> 4) << 3));
      #pragma unroll
      for (int n = 0; n < 4; n++)
        bv[n] = *(const bf16x8*)(Bs + (wc * 64 + n * 16 + (lane & 15)) * 64 + kk * 32 + ((lane >> 4) << 3));
      #pragma unroll
      for (int m = 0; m < 4; m++)
        #pragma unroll
        for (int n = 0; n < 4; n++)
          acc[m][n] = __builtin_amdgcn_mfma_f32_16x16x32_bf16(av[m], bv[n], acc[m][n], 0, 0, 0);
    }
  }

  float* Cf = (float*)Cout;
  unsigned short* Cb = (unsigned short*)Cout;
  int r0 = bm0 + wr * 64 + ((lane >> 4) << 2);
  int c0 = bn0 + wc * 64 + (lane & 15);
  #pragma unroll
  for (int n = 0; n < 4; n++){
    int c = c0 + n * 16;
    float bs = bias[c];
    #pragma unroll
    for (int m = 0; m < 4; m++){
      #pragma unroll
      for (int j = 0; j < 4; j++){
        int r = r0 + m * 16 + j;
        float v = acc[m][n][j] + bs;
        if (MODE == 0){
          Cf[(size_t)r * N + c] = v;
        } else if (MODE == 1){
          Cb[(size_t)r * N + c] = f2bf(v);
        } else {
          float gel = 0.5f * v * (1.f + erff(v * 0.70710678118f));
          Cb[(size_t)r * N + c] = f2bf(gel);
        }
      }
    }
  }
}

// ---------------- attention: per-thread online-softmax flash ----------------
// qkv: bf16 [4096][2304] (Q|K|V per row). grid (qchunk=4, h=12, b=8), block 128.
__global__ __launch_bounds__(128) void k_attn(const unsigned short* __restrict__ qkv,
                                              const int* __restrict__ mask,
                                              unsigned short* __restrict__ ctx){
  int qc = blockIdx.x, h = blockIdx.y, b = blockIdx.z;
  int t = threadIdx.x; // 128
  __shared__ __attribute__((aligned(16))) float Ks[64][64];
  __shared__ __attribute__((aligned(16))) float Vs[64][64];
  __shared__ float biasS[64];
  int qrow = b * 512 + qc * 128 + t;
  const unsigned short* qp = qkv + (size_t)qrow * 2304 + h * 64;
  float q[64];
  #pragma unroll
  for (int i = 0; i < 8; i++){
    u16x8 v = *(const u16x8*)(qp + i * 8);
    #pragma unroll
    for (int j = 0; j < 8; j++) q[i * 8 + j] = bf2f(v[j]);
  }
  float m = -1e30f, lsum = 0.f;
  float acc[64];
  #pragma unroll
  for (int d = 0; d < 64; d++) acc[d] = 0.f;

  for (int c = 0; c < 8; c++){
    __syncthreads();
    #pragma unroll
    for (int u = 0; u < 4; u++){
      int un = t + u * 128;
      int jj = un >> 3, seg = un & 7;
      size_t base = ((size_t)(b * 512 + c * 64 + jj)) * 2304 + h * 64 + seg * 8;
      u16x8 kv = *(const u16x8*)(qkv + base + 768);
      u16x8 vv = *(const u16x8*)(qkv + base + 1536);
      #pragma unroll
      for (int j = 0; j < 8; j++){
        Ks[jj][seg * 8 + j] = bf2f(kv[j]);
        Vs[jj][seg * 8 + j] = bf2f(vv[j]);
      }
    }
    if (t < 64) biasS[t] = (1.f - (float)mask[b * 512 + c * 64 + t]) * -1e9f;
    __syncthreads();
    for (int j = 0; j < 64; j++){
      float s = 0.f;
      #pragma unroll
      for (int d = 0; d < 64; d++) s += q[d] * Ks[j][d];
      s = s * 0.125f + biasS[j];
      if (s <= m){
        float p = __expf(s - m);
        lsum += p;
        #pragma unroll
        for (int d = 0; d < 64; d++) acc[d] += p * Vs[j][d];
      } else {
        float corr = __expf(m - s);
        m = s;
        lsum = lsum * corr + 1.f;
        #pragma unroll
        for (int d = 0; d < 64; d++) acc[d] = acc[d] * corr + Vs[j][d];
      }
    }
  }
  float inv = 1.f / lsum;
  unsigned short* op = ctx + (size_t)qrow * 768 + h * 64;
  #pragma unroll
  for (int i = 0; i < 8; i++){
    u16x8 o;
    #pragma unroll
    for (int j = 0; j < 8; j++) o[j] = f2bf(acc[i * 8 + j] * inv);
    *(u16x8*)(op + i * 8) = o;
  }
}

// ---------------- span heads: 4 dot-products per row ----------------
__global__ __launch_bounds__(256) void k_heads(const float* __restrict__ x,
                        const float* __restrict__ sw, const float* __restrict__ sb,
                        const float* __restrict__ ew, const float* __restrict__ eb,
                        const float* __restrict__ mw,
                        float* __restrict__ out, float* __restrict__ sproj, float* __restrict__ eproj){
  int row = blockIdx.x;
  int t = threadIdx.x;
  float a0 = 0.f, a1 = 0.f, a2 = 0.f, a3 = 0.f;
  #pragma unroll
  for (int i = 0; i < 3; i++){
    int c = t + i * 256;
    float v = x[(size_t)row * 768 + c];
    a0 += v * sw[c]; a1 += v * ew[c]; a2 += v * mw[c]; a3 += v * mw[768 + c];
  }
  #pragma unroll
  for (int o = 32; o > 0; o >>= 1){
    a0 += __shfl_down(a0, o); a1 += __shfl_down(a1, o);
    a2 += __shfl_down(a2, o); a3 += __shfl_down(a3, o);
  }
  __shared__ float red[4][4];
  int wv = t >> 6;
  if ((t & 63) == 0){ red[0][wv] = a0; red[1][wv] = a1; red[2][wv] = a2; red[3][wv] = a3; }
  __syncthreads();
  if (t == 0){
    float s0 = red[0][0] + red[0][1] + red[0][2] + red[0][3];
    float s1 = red[1][0] + red[1][1] + red[1][2] + red[1][3];
    float s2 = red[2][0] + red[2][1] + red[2][2] + red[2][3];
    float s3 = red[3][0] + red[3][1] + red[3][2] + red[3][3];
    out[row] = s0 + sb[0];
    out[4096 + row] = s1 + eb[0];
    sproj[row] = s2;
    eproj[row] = s3;
  }
}

// match_logit[b,i,j] = sproj[b,i] + eproj[b,j] + mb
__global__ __launch_bounds__(256) void k_match(const float* __restrict__ sproj, const float* __restrict__ eproj,
                        const float* __restrict__ mb, float* __restrict__ out){
  int idx = blockIdx.x * 256 + threadIdx.x;   // 524288 threads, 4 j each
  int j4 = idx & 127;
  int rest = idx >> 7;                        // b*512 + i
  float sp = sproj[rest] + mb[0];
  const float* ep = eproj + ((rest >> 9) << 9) + j4 * 4;
  float4 r;
  r.x = sp + ep[0]; r.y = sp + ep[1]; r.z = sp + ep[2]; r.w = sp + ep[3];
  ((float4*)(out + 8192))[idx] = r;
}

extern "C" void kernel_launch(void* const* d_in, const int* in_sizes, int n_in,
                              void* d_out, int out_size, void* d_ws, size_t ws_size,
                              hipStream_t stream){
  (void)in_sizes; (void)n_in; (void)out_size; (void)ws_size;
  const int*   ids  = (const int*)d_in[0];
  const int*   tts  = (const int*)d_in[1];
  const int*   mask = (const int*)d_in[2];
  const float* we   = (const float*)d_in[3];
  const float* pe   = (const float*)d_in[4];
  const float* te   = (const float*)d_in[5];
  const float* eg   = (const float*)d_in[6];
  const float* ebv  = (const float*)d_in[7];
  const float* Wq   = (const float*)d_in[8];
  const float* bq   = (const float*)d_in[9];
  const float* Wk   = (const float*)d_in[10];
  const float* bk   = (const float*)d_in[11];
  const float* Wv   = (const float*)d_in[12];
  const float* bv   = (const float*)d_in[13];
  const float* Wo   = (const float*)d_in[14];
  const float* bo   = (const float*)d_in[15];
  const float* ag   = (const float*)d_in[16];
  const float* ab   = (const float*)d_in[17];
  const float* W1   = (const float*)d_in[18];
  const float* b1   = (const float*)d_in[19];
  const float* W2   = (const float*)d_in[20];
  const float* b2   = (const float*)d_in[21];
  const float* fg   = (const float*)d_in[22];
  const float* fb   = (const float*)d_in[23];
  const float* sw   = (const float*)d_in[24];
  const float* sb   = (const float*)d_in[25];
  const float* ew   = (const float*)d_in[26];
  const float* ebd  = (const float*)d_in[27];
  const float* mw   = (const float*)d_in[28];
  const float* mb   = (const float*)d_in[29];
  float* out = (float*)d_out;

  // workspace layout (bytes)
  char* ws = (char*)d_ws;
  float* X      = (float*)(ws);                       // 12582912
  float* Y      = (float*)(ws + 12582912);            // 12582912
  float* SPROJ  = (float*)(ws + 25165824);            // 16384
  float* EPROJ  = (float*)(ws + 25182208);            // 16384
  float* BQKV   = (float*)(ws + 25198592);            // 36864
  unsigned short* XB    = (unsigned short*)(ws + 25235456);   // 6291456
  unsigned short* QKV   = (unsigned short*)(ws + 31526912);   // 18874368
  unsigned short* CTX   = (unsigned short*)(ws + 50401280);   // 6291456
  unsigned short* HBUF  = (unsigned short*)(ws + 56692736);   // 25165824
  unsigned short* WTALL = (unsigned short*)(ws + 81858560);   // 56623104  (end ~138.5MB)

  k_prep_weights<<<27648, dim3(32, 8), 0, stream>>>(Wq, Wk, Wv, Wo, W1, W2, WTALL);
  k_prep_bias<<<36, 256, 0, stream>>>(bq, bk, bv, BQKV);
  k_embed_ln<<<4096, 256, 0, stream>>>(ids, tts, we, pe, te, eg, ebv, X, XB);

  for (int l = 0; l < NL_; l++){
    unsigned short* wt = WTALL + (size_t)l * 7077888;
    k_gemm<1><<<dim3(18, 32), 256, 0, stream>>>(XB, wt, BQKV + l * 2304, QKV, 4096, 2304, 768);
    k_attn<<<dim3(4, 12, 8), 128, 0, stream>>>(QKV, mask, CTX);
    k_gemm<0><<<dim3(6, 32), 256, 0, stream>>>(CTX, wt + 1769472, bo + l * 768, Y, 4096, 768, 768);
    k_add_ln<<<4096, 256, 0, stream>>>(X, Y, ag + l * 768, ab + l * 768, X, XB);
    k_gemm<2><<<dim3(24, 32), 256, 0, stream>>>(XB, wt + 2359296, b1 + l * 3072, HBUF, 4096, 3072, 768);
    k_gemm<0><<<dim3(6, 32), 256, 0, stream>>>(HBUF, wt + 4718592, b2 + l * 768, Y, 4096, 768, 3072);
    k_add_ln<<<4096, 256, 0, stream>>>(X, Y, fg + l * 768, fb + l * 768, X, XB);
  }

  k_heads<<<4096, 256, 0, stream>>>(X, sw, sb, ew, ebd, mw, out, SPROJ, EPROJ);
  k_match<<<2048, 256, 0, stream>>>(SPROJ, EPROJ, mb, out);
}

// Round 2
// 950.951 us; speedup vs baseline: 2.3415x; 2.3415x over previous
//
#include <hip/hip_runtime.h>

#define B_   8
#define L_   512
#define H_   768
#define NH_  12
#define DFF_ 3072
#define NL_  4
#define HD_  64
#define M_   4096

typedef __bf16 bf16x8 __attribute__((ext_vector_type(8)));
typedef float f32x4 __attribute__((ext_vector_type(4)));
typedef unsigned short u16x8 __attribute__((ext_vector_type(8)));

__device__ inline float bf2f(unsigned short u){
  union { unsigned int i; float f; } v; v.i = ((unsigned int)u) << 16; return v.f;
}
__device__ inline unsigned short f2bf(float f){
  union { float f; unsigned int i; } v; v.f = f;
  unsigned int x = v.i;
  return (unsigned short)((x + 0x7fffu + ((x >> 16) & 1u)) >> 16);
}

// ---------------- weight prep: transpose fp32 [R][C] -> bf16 [C][R] ----------------
__global__ void k_prep_weights(const float* __restrict__ Wq, const float* __restrict__ Wk,
                               const float* __restrict__ Wv, const float* __restrict__ Wo,
                               const float* __restrict__ W1, const float* __restrict__ W2,
                               unsigned short* __restrict__ wTall){
  __shared__ float tile[32][33];
  int id = blockIdx.x;
  int layer = id / 6912;
  int r = id % 6912;
  unsigned short* wt = wTall + (size_t)layer * 7077888;
  const float* src; unsigned short* dst; int R, C, tr;
  if (r < 2304){
    int mat = r / 576; tr = r % 576; R = 768; C = 768;
    const float* s;
    if (mat == 0) s = Wq; else if (mat == 1) s = Wk; else if (mat == 2) s = Wv; else s = Wo;
    src = s + (size_t)layer * 589824;
    dst = wt + (size_t)mat * 589824;
  } else if (r < 4608){
    tr = r - 2304; R = 768; C = 3072;
    src = W1 + (size_t)layer * 2359296; dst = wt + 2359296;
  } else {
    tr = r - 4608; R = 3072; C = 768;
    src = W2 + (size_t)layer * 2359296; dst = wt + 4718592;
  }
  int tilesC = C >> 5;
  int r0 = (tr / tilesC) << 5, c0 = (tr % tilesC) << 5;
  int tx = threadIdx.x, ty = threadIdx.y; // (32,8)
  #pragma unroll
  for (int i = 0; i < 32; i += 8)
    tile[ty + i][tx] = src[(size_t)(r0 + ty + i) * C + c0 + tx];
  __syncthreads();
  #pragma unroll
  for (int j = 0; j < 32; j += 8)
    dst[(size_t)(c0 + ty + j) * R + r0 + tx] = f2bf(tile[tx][ty + j]);
}

// concat qkv bias per layer: [NL][2304]
__global__ void k_prep_bias(const float* __restrict__ bq, const float* __restrict__ bk,
                            const float* __restrict__ bv, float* __restrict__ out){
  int i = blockIdx.x * 256 + threadIdx.x; // 4*2304
  int layer = i / 2304, c = i % 2304;
  float v;
  if (c < 768) v = bq[layer * 768 + c];
  else if (c < 1536) v = bk[layer * 768 + c - 768];
  else v = bv[layer * 768 + c - 1536];
  out[i] = v;
}

// ---------------- embedding + LN ----------------
__global__ __launch_bounds__(256) void k_embed_ln(const int* __restrict__ ids, const int* __restrict__ tts,
                           const float* __restrict__ we, const float* __restrict__ pe,
                           const float* __restrict__ te, const float* __restrict__ g,
                           const float* __restrict__ b, float* __restrict__ x,
                           unsigned short* __restrict__ xb){
  int row = blockIdx.x;           // 4096
  int l = row & 511;
  int id = ids[row], tt = tts[row];
  int t = threadIdx.x;            // 256
  float v[3]; float s = 0.f, s2 = 0.f;
  #pragma unroll
  for (int i = 0; i < 3; i++){
    int c = t + i * 256;
    float val = we[(size_t)id * 768 + c] + pe[(size_t)l * 768 + c] + te[(size_t)tt * 768 + c];
    v[i] = val; s += val; s2 += val * val;
  }
  #pragma unroll
  for (int o = 32; o > 0; o >>= 1){ s += __shfl_down(s, o); s2 += __shfl_down(s2, o); }
  __shared__ float red[2][4];
  int wv = t >> 6;
  if ((t & 63) == 0){ red[0][wv] = s; red[1][wv] = s2; }
  __syncthreads();
  s = red[0][0] + red[0][1] + red[0][2] + red[0][3];
  s2 = red[1][0] + red[1][1] + red[1][2] + red[1][3];
  float mean = s * (1.f / 768.f);
  float var = s2 * (1.f / 768.f) - mean * mean;
  float rstd = rsqrtf(var + 1e-12f);
  #pragma unroll
  for (int i = 0; i < 3; i++){
    int c = t + i * 256;
    float nv = (v[i] - mean) * rstd * g[c] + b[c];
    x[(size_t)row * 768 + c] = nv;
    xb[(size_t)row * 768 + c] = f2bf(nv);
  }
}

// ---------------- residual add + LN (in-place on x) ----------------
__global__ __launch_bounds__(256) void k_add_ln(const float* __restrict__ xin, const float* __restrict__ y,
                         const float* __restrict__ g, const float* __restrict__ b,
                         float* __restrict__ x, unsigned short* __restrict__ xb){
  int row = blockIdx.x;
  int t = threadIdx.x;
  float v[3]; float s = 0.f, s2 = 0.f;
  #pragma unroll
  for (int i = 0; i < 3; i++){
    int c = t + i * 256;
    float val = xin[(size_t)row * 768 + c] + y[(size_t)row * 768 + c];
    v[i] = val; s += val; s2 += val * val;
  }
  #pragma unroll
  for (int o = 32; o > 0; o >>= 1){ s += __shfl_down(s, o); s2 += __shfl_down(s2, o); }
  __shared__ float red[2][4];
  int wv = t >> 6;
  if ((t & 63) == 0){ red[0][wv] = s; red[1][wv] = s2; }
  __syncthreads();
  s = red[0][0] + red[0][1] + red[0][2] + red[0][3];
  s2 = red[1][0] + red[1][1] + red[1][2] + red[1][3];
  float mean = s * (1.f / 768.f);
  float var = s2 * (1.f / 768.f) - mean * mean;
  float rstd = rsqrtf(var + 1e-12f);
  #pragma unroll
  for (int i = 0; i < 3; i++){
    int c = t + i * 256;
    float nv = (v[i] - mean) * rstd * g[c] + b[c];
    x[(size_t)row * 768 + c] = nv;
    xb[(size_t)row * 768 + c] = f2bf(nv);
  }
}

// ---------------- bf16 MFMA GEMM: C[M][N] = A[M][K] @ BT[N][K]^T + bias ----------------
template<int MODE>
__global__ __launch_bounds__(256) void k_gemm(const unsigned short* __restrict__ A,
                                              const unsigned short* __restrict__ BT,
                                              const float* __restrict__ bias,
                                              void* __restrict__ Cout,
                                              int M, int N, int K){
  __shared__ __attribute__((aligned(16))) unsigned short As[128 * 64];
  __shared__ __attribute__((aligned(16))) unsigned short Bs[128 * 64];
  int tid = threadIdx.x;
  int lane = tid & 63, wave = tid >> 6;
  int bm0 = blockIdx.y * 128, bn0 = blockIdx.x * 128;
  int wr = wave >> 1, wc = wave & 1;

  f32x4 acc[4][4];
  #pragma unroll
  for (int m = 0; m < 4; m++)
    #pragma unroll
    for (int n = 0; n < 4; n++)
      acc[m][n] = (f32x4){0.f, 0.f, 0.f, 0.f};

  const unsigned short* gaBase = A + (size_t)(bm0 + (lane >> 3)) * K + ((lane & 7) << 3);
  const unsigned short* gbBase = BT + (size_t)(bn0 + (lane >> 3)) * K + ((lane & 7) << 3);

  int nk = K >> 6;
  for (int t = 0; t < nk; t++){
    __syncthreads();
    const unsigned short* gA = gaBase + (t << 6);
    const unsigned short* gB = gbBase + (t << 6);
    #pragma unroll
    for (int i = 0; i < 4; i++){
      int ro = (wave * 4 + i) * 8;
      __builtin_amdgcn_global_load_lds(
        (const __attribute__((address_space(1))) void*)(gA + (size_t)ro * K),
        (__attribute__((address_space(3))) void*)(As + (wave * 4 + i) * 512), 16, 0, 0);
      __builtin_amdgcn_global_load_lds(
        (const __attribute__((address_space(1))) void*)(gB + (size_t)ro * K),
        (__attribute__((address_space(3))) void*)(Bs + (wave * 4 + i) * 512), 16, 0, 0);
    }
    __syncthreads();
    #pragma unroll
    for (int kk = 0; kk < 2; kk++){
      bf16x8 av[4], bv[4];
      #pragma unroll
      for (int m = 0; m < 4; m++)
        av[m] = *(const bf16x8*)(As + (wr * 64 + m * 16 + (lane & 15)) * 64 + kk * 32 + ((lane >> 4) << 3));
      #pragma unroll
      for (int n = 0; n < 4; n++)
        bv[n] = *(const bf16x8*)(Bs + (wc * 64 + n * 16 + (lane & 15)) * 64 + kk * 32 + ((lane >> 4) << 3));
      #pragma unroll
      for (int m = 0; m < 4; m++)
        #pragma unroll
        for (int n = 0; n < 4; n++)
          acc[m][n] = __builtin_amdgcn_mfma_f32_16x16x32_bf16(av[m], bv[n], acc[m][n], 0, 0, 0);
    }
  }

  float* Cf = (float*)Cout;
  unsigned short* Cb = (unsigned short*)Cout;
  int r0 = bm0 + wr * 64 + ((lane >> 4) << 2);
  int c0 = bn0 + wc * 64 + (lane & 15);
  #pragma unroll
  for (int n = 0; n < 4; n++){
    int c = c0 + n * 16;
    float bs = bias[c];
    #pragma unroll
    for (int m = 0; m < 4; m++){
      #pragma unroll
      for (int j = 0; j < 4; j++){
        int r = r0 + m * 16 + j;
        float v = acc[m][n][j] + bs;
        if (MODE == 0){
          Cf[(size_t)r * N + c] = v;
        } else if (MODE == 1){
          Cb[(size_t)r * N + c] = f2bf(v);
        } else {
          float gel = 0.5f * v * (1.f + erff(v * 0.70710678118f));
          Cb[(size_t)r * N + c] = f2bf(gel);
        }
      }
    }
  }
}

// ---------------- MFMA flash attention ----------------
// qkv: bf16 [4096][2304] (Q|K|V per row). grid (8 qtiles, 12 h, 8 b), block 256 (4 waves).
// Each wave owns 16 q-rows; K/V tiles of 64 rows iterated 8x.
// Frag layouts (verified in GEMM): A: row=l&15, k=(l>>4)*8+j ; B(T): n=l&15, k=(l>>4)*8+j ;
// C/D: col=l&15, row=4*(l>>4)+j.
__global__ __launch_bounds__(256) void k_attn_mfma(const unsigned short* __restrict__ qkv,
                                                   const int* __restrict__ mask,
                                                   unsigned short* __restrict__ ctx){
  int qt = blockIdx.x, h = blockIdx.y, b = blockIdx.z;
  int tid = threadIdx.x;
  int lane = tid & 63, w = tid >> 6;
  int lr = lane & 15, lg = lane >> 4;

  __shared__ __attribute__((aligned(16))) unsigned short Ks[64][72];   // K rows, pad 72
  __shared__ __attribute__((aligned(16))) unsigned short VsT[64][72];  // V transposed [d][k]
  __shared__ __attribute__((aligned(16))) unsigned short Ps[4][16][72];// per-wave P tile
  __shared__ float biasS[64];

  // Q A-fragments, loaded once from global
  int qrow = b * 512 + qt * 64 + w * 16 + lr;
  const unsigned short* qp = qkv + (size_t)qrow * 2304 + h * 64 + lg * 8;
  bf16x8 qa[2];
  qa[0] = *(const bf16x8*)(qp);
  qa[1] = *(const bf16x8*)(qp + 32);

  f32x4 oacc[4];
  #pragma unroll
  for (int dt = 0; dt < 4; dt++) oacc[dt] = (f32x4){0.f, 0.f, 0.f, 0.f};
  float mrow[4], lrow[4];
  #pragma unroll
  for (int j = 0; j < 4; j++){ mrow[j] = -1e30f; lrow[j] = 0.f; }

  for (int c = 0; c < 8; c++){
    __syncthreads();  // previous iteration's LDS reads done
    // stage K: row-major [kr][d], 4 threads per row
    {
      int r = tid >> 2, d0 = (tid & 3) << 4;
      const unsigned short* kp = qkv + (size_t)(b * 512 + c * 64 + r) * 2304 + 768 + h * 64 + d0;
      u16x8 k0 = *(const u16x8*)kp;
      u16x8 k1 = *(const u16x8*)(kp + 8);
      *(u16x8*)(&Ks[r][d0]) = k0;
      *(u16x8*)(&Ks[r][d0 + 8]) = k1;
    }
    // stage V transposed: thread owns one k-col (lane-major k -> conflict-free b16 writes)
    {
      int kv = tid & 63, d0 = (tid >> 6) << 4;
      const unsigned short* vp = qkv + (size_t)(b * 512 + c * 64 + kv) * 2304 + 1536 + h * 64 + d0;
      u16x8 v0 = *(const u16x8*)vp;
      u16x8 v1 = *(const u16x8*)(vp + 8);
      #pragma unroll
      for (int j2 = 0; j2 < 8; j2++){
        VsT[d0 + j2][kv] = (unsigned short)v0[j2];
        VsT[d0 + 8 + j2][kv] = (unsigned short)v1[j2];
      }
    }
    if (tid < 64) biasS[tid] = (1.f - (float)mask[b * 512 + c * 64 + tid]) * -1e9f;
    __syncthreads();

    // S = Q K^T  (16q x 64k per wave)
    f32x4 sacc[4];
    #pragma unroll
    for (int n = 0; n < 4; n++) sacc[n] = (f32x4){0.f, 0.f, 0.f, 0.f};
    #pragma unroll
    for (int kk = 0; kk < 2; kk++){
      bf16x8 kb[4];
      #pragma unroll
      for (int n = 0; n < 4; n++)
        kb[n] = *(const bf16x8*)(&Ks[lr + 16 * n][lg * 8 + 32 * kk]);
      #pragma unroll
      for (int n = 0; n < 4; n++)
        sacc[n] = __builtin_amdgcn_mfma_f32_16x16x32_bf16(qa[kk], kb[n], sacc[n], 0, 0, 0);
    }

    // wave-parallel online softmax; lane holds rows 4*lg+j, col lr+16n
    float pv[4][4]; // [n][j]
    #pragma unroll
    for (int n = 0; n < 4; n++){
      float bsv = biasS[lr + 16 * n];
      #pragma unroll
      for (int j = 0; j < 4; j++) pv[n][j] = sacc[n][j] * 0.125f + bsv;
    }
    #pragma unroll
    for (int j = 0; j < 4; j++){
      float mx = fmaxf(fmaxf(pv[0][j], pv[1][j]), fmaxf(pv[2][j], pv[3][j]));
      mx = fmaxf(mx, __shfl_xor(mx, 1));
      mx = fmaxf(mx, __shfl_xor(mx, 2));
      mx = fmaxf(mx, __shfl_xor(mx, 4));
      mx = fmaxf(mx, __shfl_xor(mx, 8));
      float mnew = fmaxf(mrow[j], mx);
      float corr = __expf(mrow[j] - mnew);
      float ps = 0.f;
      #pragma unroll
      for (int n = 0; n < 4; n++){
        pv[n][j] = __expf(pv[n][j] - mnew);
        ps += pv[n][j];
      }
      ps += __shfl_xor(ps, 1);
      ps += __shfl_xor(ps, 2);
      ps += __shfl_xor(ps, 4);
      ps += __shfl_xor(ps, 8);
      lrow[j] = lrow[j] * corr + ps;
      mrow[j] = mnew;
      #pragma unroll
      for (int dt = 0; dt < 4; dt++) oacc[dt][j] *= corr;
    }

    // P -> per-wave LDS (reshape to A-frag layout)
    #pragma unroll
    for (int n = 0; n < 4; n++)
      #pragma unroll
      for (int j = 0; j < 4; j++)
        Ps[w][4 * lg + j][lr + 16 * n] = f2bf(pv[n][j]);

    // O += P V  (same-wave LDS dependency; compiler inserts lgkmcnt)
    #pragma unroll
    for (int kk = 0; kk < 2; kk++){
      bf16x8 pa = *(const bf16x8*)(&Ps[w][lr][lg * 8 + 32 * kk]);
      bf16x8 vb[4];
      #pragma unroll
      for (int dt = 0; dt < 4; dt++)
        vb[dt] = *(const bf16x8*)(&VsT[lr + 16 * dt][lg * 8 + 32 * kk]);
      #pragma unroll
      for (int dt = 0; dt < 4; dt++)
        oacc[dt] = __builtin_amdgcn_mfma_f32_16x16x32_bf16(pa, vb[dt], oacc[dt], 0, 0, 0);
    }
  }

  // epilogue: normalize and write ctx[q][h*64+d]
  #pragma unroll
  for (int j = 0; j < 4; j++){
    float inv = 1.f / lrow[j];
    int row = b * 512 + qt * 64 + w * 16 + 4 * lg + j;
    unsigned short* o = ctx + (size_t)row * 768 + h * 64;
    #pragma unroll
    for (int dt = 0; dt < 4; dt++)
      o[lr + 16 * dt] = f2bf(oacc[dt][j] * inv);
  }
}

// ---------------- span heads: 4 dot-products per row ----------------
__global__ __launch_bounds__(256) void k_heads(const float* __restrict__ x,
                        const float* __restrict__ sw, const float* __restrict__ sb,
                        const float* __restrict__ ew, const float* __restrict__ eb,
                        const float* __restrict__ mw,
                        float* __restrict__ out, float* __restrict__ sproj, float* __restrict__ eproj){
  int row = blockIdx.x;
  int t = threadIdx.x;
  float a0 = 0.f, a1 = 0.f, a2 = 0.f, a3 = 0.f;
  #pragma unroll
  for (int i = 0; i < 3; i++){
    int c = t + i * 256;
    float v = x[(size_t)row * 768 + c];
    a0 += v * sw[c]; a1 += v * ew[c]; a2 += v * mw[c]; a3 += v * mw[768 + c];
  }
  #pragma unroll
  for (int o = 32; o > 0; o >>= 1){
    a0 += __shfl_down(a0, o); a1 += __shfl_down(a1, o);
    a2 += __shfl_down(a2, o); a3 += __shfl_down(a3, o);
  }
  __shared__ float red[4][4];
  int wv = t >> 6;
  if ((t & 63) == 0){ red[0][wv] = a0; red[1][wv] = a1; red[2][wv] = a2; red[3][wv] = a3; }
  __syncthreads();
  if (t == 0){
    float s0 = red[0][0] + red[0][1] + red[0][2] + red[0][3];
    float s1 = red[1][0] + red[1][1] + red[1][2] + red[1][3];
    float s2 = red[2][0] + red[2][1] + red[2][2] + red[2][3];
    float s3 = red[3][0] + red[3][1] + red[3][2] + red[3][3];
    out[row] = s0 + sb[0];
    out[4096 + row] = s1 + eb[0];
    sproj[row] = s2;
    eproj[row] = s3;
  }
}

// match_logit[b,i,j] = sproj[b,i] + eproj[b,j] + mb
__global__ __launch_bounds__(256) void k_match(const float* __restrict__ sproj, const float* __restrict__ eproj,
                        const float* __restrict__ mb, float* __restrict__ out){
  int idx = blockIdx.x * 256 + threadIdx.x;   // 524288 threads, 4 j each
  int j4 = idx & 127;
  int rest = idx >> 7;                        // b*512 + i
  float sp = sproj[rest] + mb[0];
  const float* ep = eproj + ((rest >> 9) << 9) + j4 * 4;
  float4 r;
  r.x = sp + ep[0]; r.y = sp + ep[1]; r.z = sp + ep[2]; r.w = sp + ep[3];
  ((float4*)(out + 8192))[idx] = r;
}

extern "C" void kernel_launch(void* const* d_in, const int* in_sizes, int n_in,
                              void* d_out, int out_size, void* d_ws, size_t ws_size,
                              hipStream_t stream){
  (void)in_sizes; (void)n_in; (void)out_size; (void)ws_size;
  const int*   ids  = (const int*)d_in[0];
  const int*   tts  = (const int*)d_in[1];
  const int*   mask = (const int*)d_in[2];
  const float* we   = (const float*)d_in[3];
  const float* pe   = (const float*)d_in[4];
  const float* te   = (const float*)d_in[5];
  const float* eg   = (const float*)d_in[6];
  const float* ebv  = (const float*)d_in[7];
  const float* Wq   = (const float*)d_in[8];
  const float* bq   = (const float*)d_in[9];
  const float* Wk   = (const float*)d_in[10];
  const float* bk   = (const float*)d_in[11];
  const float* Wv   = (const float*)d_in[12];
  const float* bv   = (const float*)d_in[13];
  const float* Wo   = (const float*)d_in[14];
  const float* bo   = (const float*)d_in[15];
  const float* ag   = (const float*)d_in[16];
  const float* ab   = (const float*)d_in[17];
  const float* W1   = (const float*)d_in[18];
  const float* b1   = (const float*)d_in[19];
  const float* W2   = (const float*)d_in[20];
  const float* b2   = (const float*)d_in[21];
  const float* fg   = (const float*)d_in[22];
  const float* fb   = (const float*)d_in[23];
  const float* sw   = (const float*)d_in[24];
  const float* sb   = (const float*)d_in[25];
  const float* ew   = (const float*)d_in[26];
  const float* ebd  = (const float*)d_in[27];
  const float* mw   = (const float*)d_in[28];
  const float* mb   = (const float*)d_in[29];
  float* out = (float*)d_out;

  // workspace layout (bytes)
  char* ws = (char*)d_ws;
  float* X      = (float*)(ws);                       // 12582912
  float* Y      = (float*)(ws + 12582912);            // 12582912
  float* SPROJ  = (float*)(ws + 25165824);            // 16384
  float* EPROJ  = (float*)(ws + 25182208);            // 16384
  float* BQKV   = (float*)(ws + 25198592);            // 36864
  unsigned short* XB    = (unsigned short*)(ws + 25235456);   // 6291456
  unsigned short* QKV   = (unsigned short*)(ws + 31526912);   // 18874368
  unsigned short* CTX   = (unsigned short*)(ws + 50401280);   // 6291456
  unsigned short* HBUF  = (unsigned short*)(ws + 56692736);   // 25165824
  unsigned short* WTALL = (unsigned short*)(ws + 81858560);   // 56623104  (end ~138.5MB)

  k_prep_weights<<<27648, dim3(32, 8), 0, stream>>>(Wq, Wk, Wv, Wo, W1, W2, WTALL);
  k_prep_bias<<<36, 256, 0, stream>>>(bq, bk, bv, BQKV);
  k_embed_ln<<<4096, 256, 0, stream>>>(ids, tts, we, pe, te, eg, ebv, X, XB);

  for (int l = 0; l < NL_; l++){
    unsigned short* wt = WTALL + (size_t)l * 7077888;
    k_gemm<1><<<dim3(18, 32), 256, 0, stream>>>(XB, wt, BQKV + l * 2304, QKV, 4096, 2304, 768);
    k_attn_mfma<<<dim3(8, 12, 8), 256, 0, stream>>>(QKV, mask, CTX);
    k_gemm<0><<<dim3(6, 32), 256, 0, stream>>>(CTX, wt + 1769472, bo + l * 768, Y, 4096, 768, 768);
    k_add_ln<<<4096, 256, 0, stream>>>(X, Y, ag + l * 768, ab + l * 768, X, XB);
    k_gemm<2><<<dim3(24, 32), 256, 0, stream>>>(XB, wt + 2359296, b1 + l * 3072, HBUF, 4096, 3072, 768);
    k_gemm<0><<<dim3(6, 32), 256, 0, stream>>>(HBUF, wt + 4718592, b2 + l * 768, Y, 4096, 768, 3072);
    k_add_ln<<<4096, 256, 0, stream>>>(X, Y, fg + l * 768, fb + l * 768, X, XB);
  }

  k_heads<<<4096, 256, 0, stream>>>(X, sw, sb, ew, ebd, mw, out, SPROJ, EPROJ);
  k_match<<<2048, 256, 0, stream>>>(SPROJ, EPROJ, mb, out);
}

// Round 3
// 765.848 us; speedup vs baseline: 2.9075x; 1.2417x over previous
//
#include <hip/hip_runtime.h>

#define B_   8
#define L_   512
#define H_   768
#define NH_  12
#define DFF_ 3072
#define NL_  4
#define HD_  64
#define M_   4096

typedef __bf16 bf16x8 __attribute__((ext_vector_type(8)));
typedef float f32x4 __attribute__((ext_vector_type(4)));
typedef unsigned short u16x8 __attribute__((ext_vector_type(8)));

__device__ inline float bf2f(unsigned short u){
  union { unsigned int i; float f; } v; v.i = ((unsigned int)u) << 16; return v.f;
}
__device__ inline unsigned short f2bf(float f){
  union { float f; unsigned int i; } v; v.f = f;
  unsigned int x = v.i;
  return (unsigned short)((x + 0x7fffu + ((x >> 16) & 1u)) >> 16);
}

// ---------------- weight prep: transpose fp32 [R][C] -> bf16 [C][R] ----------------
__global__ void k_prep_weights(const float* __restrict__ Wq, const float* __restrict__ Wk,
                               const float* __restrict__ Wv, const float* __restrict__ Wo,
                               const float* __restrict__ W1, const float* __restrict__ W2,
                               unsigned short* __restrict__ wTall){
  __shared__ float tile[32][33];
  int id = blockIdx.x;
  int layer = id / 6912;
  int r = id % 6912;
  unsigned short* wt = wTall + (size_t)layer * 7077888;
  const float* src; unsigned short* dst; int R, C, tr;
  if (r < 2304){
    int mat = r / 576; tr = r % 576; R = 768; C = 768;
    const float* s;
    if (mat == 0) s = Wq; else if (mat == 1) s = Wk; else if (mat == 2) s = Wv; else s = Wo;
    src = s + (size_t)layer * 589824;
    dst = wt + (size_t)mat * 589824;
  } else if (r < 4608){
    tr = r - 2304; R = 768; C = 3072;
    src = W1 + (size_t)layer * 2359296; dst = wt + 2359296;
  } else {
    tr = r - 4608; R = 3072; C = 768;
    src = W2 + (size_t)layer * 2359296; dst = wt + 4718592;
  }
  int tilesC = C >> 5;
  int r0 = (tr / tilesC) << 5, c0 = (tr % tilesC) << 5;
  int tx = threadIdx.x, ty = threadIdx.y; // (32,8)
  #pragma unroll
  for (int i = 0; i < 32; i += 8)
    tile[ty + i][tx] = src[(size_t)(r0 + ty + i) * C + c0 + tx];
  __syncthreads();
  #pragma unroll
  for (int j = 0; j < 32; j += 8)
    dst[(size_t)(c0 + ty + j) * R + r0 + tx] = f2bf(tile[tx][ty + j]);
}

// concat qkv bias per layer: [NL][2304]
__global__ void k_prep_bias(const float* __restrict__ bq, const float* __restrict__ bk,
                            const float* __restrict__ bv, float* __restrict__ out){
  int i = blockIdx.x * 256 + threadIdx.x; // 4*2304
  int layer = i / 2304, c = i % 2304;
  float v;
  if (c < 768) v = bq[layer * 768 + c];
  else if (c < 1536) v = bk[layer * 768 + c - 768];
  else v = bv[layer * 768 + c - 1536];
  out[i] = v;
}

// ---------------- embedding + LN ----------------
__global__ __launch_bounds__(256) void k_embed_ln(const int* __restrict__ ids, const int* __restrict__ tts,
                           const float* __restrict__ we, const float* __restrict__ pe,
                           const float* __restrict__ te, const float* __restrict__ g,
                           const float* __restrict__ b, float* __restrict__ x,
                           unsigned short* __restrict__ xb){
  int row = blockIdx.x;           // 4096
  int l = row & 511;
  int id = ids[row], tt = tts[row];
  int t = threadIdx.x;            // 256
  float v[3]; float s = 0.f, s2 = 0.f;
  #pragma unroll
  for (int i = 0; i < 3; i++){
    int c = t + i * 256;
    float val = we[(size_t)id * 768 + c] + pe[(size_t)l * 768 + c] + te[(size_t)tt * 768 + c];
    v[i] = val; s += val; s2 += val * val;
  }
  #pragma unroll
  for (int o = 32; o > 0; o >>= 1){ s += __shfl_down(s, o); s2 += __shfl_down(s2, o); }
  __shared__ float red[2][4];
  int wv = t >> 6;
  if ((t & 63) == 0){ red[0][wv] = s; red[1][wv] = s2; }
  __syncthreads();
  s = red[0][0] + red[0][1] + red[0][2] + red[0][3];
  s2 = red[1][0] + red[1][1] + red[1][2] + red[1][3];
  float mean = s * (1.f / 768.f);
  float var = s2 * (1.f / 768.f) - mean * mean;
  float rstd = rsqrtf(var + 1e-12f);
  #pragma unroll
  for (int i = 0; i < 3; i++){
    int c = t + i * 256;
    float nv = (v[i] - mean) * rstd * g[c] + b[c];
    x[(size_t)row * 768 + c] = nv;
    xb[(size_t)row * 768 + c] = f2bf(nv);
  }
}

// ---------------- residual add (+ optional second partial) + LN ----------------
__global__ __launch_bounds__(256) void k_add_ln(const float* __restrict__ xin, const float* __restrict__ y,
                         const float* __restrict__ y2,
                         const float* __restrict__ g, const float* __restrict__ b,
                         float* __restrict__ x, unsigned short* __restrict__ xb){
  int row = blockIdx.x;
  int t = threadIdx.x;
  float v[3]; float s = 0.f, s2 = 0.f;
  #pragma unroll
  for (int i = 0; i < 3; i++){
    int c = t + i * 256;
    float val = xin[(size_t)row * 768 + c] + y[(size_t)row * 768 + c];
    if (y2) val += y2[(size_t)row * 768 + c];
    v[i] = val; s += val; s2 += val * val;
  }
  #pragma unroll
  for (int o = 32; o > 0; o >>= 1){ s += __shfl_down(s, o); s2 += __shfl_down(s2, o); }
  __shared__ float red[2][4];
  int wv = t >> 6;
  if ((t & 63) == 0){ red[0][wv] = s; red[1][wv] = s2; }
  __syncthreads();
  s = red[0][0] + red[0][1] + red[0][2] + red[0][3];
  s2 = red[1][0] + red[1][1] + red[1][2] + red[1][3];
  float mean = s * (1.f / 768.f);
  float var = s2 * (1.f / 768.f) - mean * mean;
  float rstd = rsqrtf(var + 1e-12f);
  #pragma unroll
  for (int i = 0; i < 3; i++){
    int c = t + i * 256;
    float nv = (v[i] - mean) * rstd * g[c] + b[c];
    x[(size_t)row * 768 + c] = nv;
    xb[(size_t)row * 768 + c] = f2bf(nv);
  }
}

// ---------------- bf16 MFMA GEMM, double-buffered pipeline ----------------
// C[M][N] = A[M][K(slice)] @ BT[N][K]^T + bias.  Ksub = K per z-slice; blockIdx.z
// selects the K-slice; z>0 writes to Cout2 (partial, no bias).
// MODE 0: f32 out; MODE 1: bf16 out; MODE 2: bf16 gelu(out)
template<int MODE>
__global__ __launch_bounds__(256) void k_gemm(const unsigned short* __restrict__ A,
                                              const unsigned short* __restrict__ BT,
                                              const float* __restrict__ bias,
                                              void* __restrict__ Cout, void* __restrict__ Cout2,
                                              int M, int N, int K, int Ksub){
  __shared__ __attribute__((aligned(16))) unsigned short smem[2][2][8192]; // [buf][A|B][128*64]
  int tid = threadIdx.x;
  int lane = tid & 63, wave = tid >> 6;
  int lr = lane & 15, lg = lane >> 4;

  // XCD-aware swizzle of flat tile id (nwg % 8 == 0 in all launches)
  int gx = gridDim.x;
  int nwg = gx * gridDim.y;
  int flat = blockIdx.y * gx + blockIdx.x;
  int cpx = nwg >> 3;
  int swz = (flat & 7) * cpx + (flat >> 3);
  int bx = swz % gx, by = swz / gx;

  int bm0 = by * 128, bn0 = bx * 128;
  int wr = wave >> 1, wc = wave & 1;
  int kz = blockIdx.z * Ksub;

  f32x4 acc[4][4];
  #pragma unroll
  for (int m = 0; m < 4; m++)
    #pragma unroll
    for (int n = 0; n < 4; n++)
      acc[m][n] = (f32x4){0.f, 0.f, 0.f, 0.f};

  const unsigned short* gaBase = A + (size_t)(bm0 + (lane >> 3)) * K + kz + ((lane & 7) << 3);
  const unsigned short* gbBase = BT + (size_t)(bn0 + (lane >> 3)) * K + kz + ((lane & 7) << 3);

  int nk = Ksub >> 6;

  auto STAGE = [&](int buf, int t){
    const unsigned short* gA = gaBase + (t << 6);
    const unsigned short* gB = gbBase + (t << 6);
    unsigned short* as = &smem[buf][0][0];
    unsigned short* bs = &smem[buf][1][0];
    #pragma unroll
    for (int i = 0; i < 4; i++){
      size_t ro = (size_t)((wave * 4 + i) * 8) * K;
      __builtin_amdgcn_global_load_lds(
        (const __attribute__((address_space(1))) void*)(gA + ro),
        (__attribute__((address_space(3))) void*)(as + (wave * 4 + i) * 512), 16, 0, 0);
      __builtin_amdgcn_global_load_lds(
        (const __attribute__((address_space(1))) void*)(gB + ro),
        (__attribute__((address_space(3))) void*)(bs + (wave * 4 + i) * 512), 16, 0, 0);
    }
  };

  auto COMPUTE = [&](int buf){
    const unsigned short* as = &smem[buf][0][0];
    const unsigned short* bs = &smem[buf][1][0];
    #pragma unroll
    for (int kk = 0; kk < 2; kk++){
      bf16x8 av[4], bv[4];
      #pragma unroll
      for (int m = 0; m < 4; m++)
        av[m] = *(const bf16x8*)(as + (wr * 64 + m * 16 + lr) * 64 + kk * 32 + lg * 8);
      #pragma unroll
      for (int n = 0; n < 4; n++)
        bv[n] = *(const bf16x8*)(bs + (wc * 64 + n * 16 + lr) * 64 + kk * 32 + lg * 8);
      #pragma unroll
      for (int m = 0; m < 4; m++)
        #pragma unroll
        for (int n = 0; n < 4; n++)
          acc[m][n] = __builtin_amdgcn_mfma_f32_16x16x32_bf16(av[m], bv[n], acc[m][n], 0, 0, 0);
    }
  };

  STAGE(0, 0);
  __syncthreads();            // drains vmcnt; tile 0 resident
  int cur = 0;
  for (int t = 0; t < nk - 1; t++){
    STAGE(cur ^ 1, t + 1);    // issue next tile's loads (in flight during compute)
    COMPUTE(cur);
    __syncthreads();          // drains vmcnt+lgkm; all waves aligned
    cur ^= 1;
  }
  COMPUTE(cur);
  __syncthreads();            // everyone done reading smem; safe to reuse for epilogue

  int r0 = wr * 64 + 4 * lg;
  int c0 = wc * 64 + lr;
  if (MODE == 0){
    // stage f32 C tile [128][128] (64 KB = whole smem), then linear coalesced copy
    float* cs = (float*)smem;
    #pragma unroll
    for (int n = 0; n < 4; n++){
      int c = c0 + 16 * n;
      float bsv = (blockIdx.z == 0) ? bias[bn0 + c] : 0.f;
      #pragma unroll
      for (int m = 0; m < 4; m++)
        #pragma unroll
        for (int j = 0; j < 4; j++)
          cs[(r0 + m * 16 + j) * 128 + c] = acc[m][n][j] + bsv;
    }
    __syncthreads();
    float* Cf = (float*)(blockIdx.z == 0 ? Cout : Cout2);
    #pragma unroll
    for (int p = 0; p < 16; p++){
      int idx = p * 1024 + tid * 4;
      int row = idx >> 7, col = idx & 127;
      f32x4 v = *(const f32x4*)(cs + idx);
      *(f32x4*)(Cf + (size_t)(bm0 + row) * N + bn0 + col) = v;
    }
  } else {
    // stage bf16 C tile [128][128] (32 KB), then linear coalesced copy
    unsigned short* cs = (unsigned short*)smem;
    #pragma unroll
    for (int n = 0; n < 4; n++){
      int c = c0 + 16 * n;
      float bsv = bias[bn0 + c];
      #pragma unroll
      for (int m = 0; m < 4; m++)
        #pragma unroll
        for (int j = 0; j < 4; j++){
          float v = acc[m][n][j] + bsv;
          if (MODE == 2) v = 0.5f * v * (1.f + erff(v * 0.70710678118f));
          cs[(r0 + m * 16 + j) * 128 + c] = f2bf(v);
        }
    }
    __syncthreads();
    unsigned short* Cb = (unsigned short*)Cout;
    #pragma unroll
    for (int p = 0; p < 8; p++){
      int idx = p * 2048 + tid * 8;
      int row = idx >> 7, col = idx & 127;
      u16x8 v = *(const u16x8*)(cs + idx);
      *(u16x8*)(Cb + (size_t)(bm0 + row) * N + bn0 + col) = v;
    }
  }
}

// ---------------- MFMA flash attention ----------------
__global__ __launch_bounds__(256) void k_attn_mfma(const unsigned short* __restrict__ qkv,
                                                   const int* __restrict__ mask,
                                                   unsigned short* __restrict__ ctx){
  int qt = blockIdx.x, h = blockIdx.y, b = blockIdx.z;
  int tid = threadIdx.x;
  int lane = tid & 63, w = tid >> 6;
  int lr = lane & 15, lg = lane >> 4;

  __shared__ __attribute__((aligned(16))) unsigned short Ks[64][72];
  __shared__ __attribute__((aligned(16))) unsigned short VsT[64][72];
  __shared__ __attribute__((aligned(16))) unsigned short Ps[4][16][72];
  __shared__ float biasS[64];

  int qrow = b * 512 + qt * 64 + w * 16 + lr;
  const unsigned short* qp = qkv + (size_t)qrow * 2304 + h * 64 + lg * 8;
  bf16x8 qa[2];
  qa[0] = *(const bf16x8*)(qp);
  qa[1] = *(const bf16x8*)(qp + 32);

  f32x4 oacc[4];
  #pragma unroll
  for (int dt = 0; dt < 4; dt++) oacc[dt] = (f32x4){0.f, 0.f, 0.f, 0.f};
  float mrow[4], lrow[4];
  #pragma unroll
  for (int j = 0; j < 4; j++){ mrow[j] = -1e30f; lrow[j] = 0.f; }

  for (int c = 0; c < 8; c++){
    __syncthreads();
    {
      int r = tid >> 2, d0 = (tid & 3) << 4;
      const unsigned short* kp = qkv + (size_t)(b * 512 + c * 64 + r) * 2304 + 768 + h * 64 + d0;
      u16x8 k0 = *(const u16x8*)kp;
      u16x8 k1 = *(const u16x8*)(kp + 8);
      *(u16x8*)(&Ks[r][d0]) = k0;
      *(u16x8*)(&Ks[r][d0 + 8]) = k1;
    }
    {
      int kv = tid & 63, d0 = (tid >> 6) << 4;
      const unsigned short* vp = qkv + (size_t)(b * 512 + c * 64 + kv) * 2304 + 1536 + h * 64 + d0;
      u16x8 v0 = *(const u16x8*)vp;
      u16x8 v1 = *(const u16x8*)(vp + 8);
      #pragma unroll
      for (int j2 = 0; j2 < 8; j2++){
        VsT[d0 + j2][kv] = (unsigned short)v0[j2];
        VsT[d0 + 8 + j2][kv] = (unsigned short)v1[j2];
      }
    }
    if (tid < 64) biasS[tid] = (1.f - (float)mask[b * 512 + c * 64 + tid]) * -1e9f;
    __syncthreads();

    f32x4 sacc[4];
    #pragma unroll
    for (int n = 0; n < 4; n++) sacc[n] = (f32x4){0.f, 0.f, 0.f, 0.f};
    #pragma unroll
    for (int kk = 0; kk < 2; kk++){
      bf16x8 kb[4];
      #pragma unroll
      for (int n = 0; n < 4; n++)
        kb[n] = *(const bf16x8*)(&Ks[lr + 16 * n][lg * 8 + 32 * kk]);
      #pragma unroll
      for (int n = 0; n < 4; n++)
        sacc[n] = __builtin_amdgcn_mfma_f32_16x16x32_bf16(qa[kk], kb[n], sacc[n], 0, 0, 0);
    }

    float pv[4][4];
    #pragma unroll
    for (int n = 0; n < 4; n++){
      float bsv = biasS[lr + 16 * n];
      #pragma unroll
      for (int j = 0; j < 4; j++) pv[n][j] = sacc[n][j] * 0.125f + bsv;
    }
    #pragma unroll
    for (int j = 0; j < 4; j++){
      float mx = fmaxf(fmaxf(pv[0][j], pv[1][j]), fmaxf(pv[2][j], pv[3][j]));
      mx = fmaxf(mx, __shfl_xor(mx, 1));
      mx = fmaxf(mx, __shfl_xor(mx, 2));
      mx = fmaxf(mx, __shfl_xor(mx, 4));
      mx = fmaxf(mx, __shfl_xor(mx, 8));
      float mnew = fmaxf(mrow[j], mx);
      float corr = __expf(mrow[j] - mnew);
      float ps = 0.f;
      #pragma unroll
      for (int n = 0; n < 4; n++){
        pv[n][j] = __expf(pv[n][j] - mnew);
        ps += pv[n][j];
      }
      ps += __shfl_xor(ps, 1);
      ps += __shfl_xor(ps, 2);
      ps += __shfl_xor(ps, 4);
      ps += __shfl_xor(ps, 8);
      lrow[j] = lrow[j] * corr + ps;
      mrow[j] = mnew;
      #pragma unroll
      for (int dt = 0; dt < 4; dt++) oacc[dt][j] *= corr;
    }

    #pragma unroll
    for (int n = 0; n < 4; n++)
      #pragma unroll
      for (int j = 0; j < 4; j++)
        Ps[w][4 * lg + j][lr + 16 * n] = f2bf(pv[n][j]);

    #pragma unroll
    for (int kk = 0; kk < 2; kk++){
      bf16x8 pa = *(const bf16x8*)(&Ps[w][lr][lg * 8 + 32 * kk]);
      bf16x8 vb[4];
      #pragma unroll
      for (int dt = 0; dt < 4; dt++)
        vb[dt] = *(const bf16x8*)(&VsT[lr + 16 * dt][lg * 8 + 32 * kk]);
      #pragma unroll
      for (int dt = 0; dt < 4; dt++)
        oacc[dt] = __builtin_amdgcn_mfma_f32_16x16x32_bf16(pa, vb[dt], oacc[dt], 0, 0, 0);
    }
  }

  #pragma unroll
  for (int j = 0; j < 4; j++){
    float inv = 1.f / lrow[j];
    int row = b * 512 + qt * 64 + w * 16 + 4 * lg + j;
    unsigned short* o = ctx + (size_t)row * 768 + h * 64;
    #pragma unroll
    for (int dt = 0; dt < 4; dt++)
      o[lr + 16 * dt] = f2bf(oacc[dt][j] * inv);
  }
}

// ---------------- span heads ----------------
__global__ __launch_bounds__(256) void k_heads(const float* __restrict__ x,
                        const float* __restrict__ sw, const float* __restrict__ sb,
                        const float* __restrict__ ew, const float* __restrict__ eb,
                        const float* __restrict__ mw,
                        float* __restrict__ out, float* __restrict__ sproj, float* __restrict__ eproj){
  int row = blockIdx.x;
  int t = threadIdx.x;
  float a0 = 0.f, a1 = 0.f, a2 = 0.f, a3 = 0.f;
  #pragma unroll
  for (int i = 0; i < 3; i++){
    int c = t + i * 256;
    float v = x[(size_t)row * 768 + c];
    a0 += v * sw[c]; a1 += v * ew[c]; a2 += v * mw[c]; a3 += v * mw[768 + c];
  }
  #pragma unroll
  for (int o = 32; o > 0; o >>= 1){
    a0 += __shfl_down(a0, o); a1 += __shfl_down(a1, o);
    a2 += __shfl_down(a2, o); a3 += __shfl_down(a3, o);
  }
  __shared__ float red[4][4];
  int wv = t >> 6;
  if ((t & 63) == 0){ red[0][wv] = a0; red[1][wv] = a1; red[2][wv] = a2; red[3][wv] = a3; }
  __syncthreads();
  if (t == 0){
    float s0 = red[0][0] + red[0][1] + red[0][2] + red[0][3];
    float s1 = red[1][0] + red[1][1] + red[1][2] + red[1][3];
    float s2 = red[2][0] + red[2][1] + red[2][2] + red[2][3];
    float s3 = red[3][0] + red[3][1] + red[3][2] + red[3][3];
    out[row] = s0 + sb[0];
    out[4096 + row] = s1 + eb[0];
    sproj[row] = s2;
    eproj[row] = s3;
  }
}

__global__ __launch_bounds__(256) void k_match(const float* __restrict__ sproj, const float* __restrict__ eproj,
                        const float* __restrict__ mb, float* __restrict__ out){
  int idx = blockIdx.x * 256 + threadIdx.x;
  int j4 = idx & 127;
  int rest = idx >> 7;
  float sp = sproj[rest] + mb[0];
  const float* ep = eproj + ((rest >> 9) << 9) + j4 * 4;
  float4 r;
  r.x = sp + ep[0]; r.y = sp + ep[1]; r.z = sp + ep[2]; r.w = sp + ep[3];
  ((float4*)(out + 8192))[idx] = r;
}

extern "C" void kernel_launch(void* const* d_in, const int* in_sizes, int n_in,
                              void* d_out, int out_size, void* d_ws, size_t ws_size,
                              hipStream_t stream){
  (void)in_sizes; (void)n_in; (void)out_size; (void)ws_size;
  const int*   ids  = (const int*)d_in[0];
  const int*   tts  = (const int*)d_in[1];
  const int*   mask = (const int*)d_in[2];
  const float* we   = (const float*)d_in[3];
  const float* pe   = (const float*)d_in[4];
  const float* te   = (const float*)d_in[5];
  const float* eg   = (const float*)d_in[6];
  const float* ebv  = (const float*)d_in[7];
  const float* Wq   = (const float*)d_in[8];
  const float* bq   = (const float*)d_in[9];
  const float* Wk   = (const float*)d_in[10];
  const float* bk   = (const float*)d_in[11];
  const float* Wv   = (const float*)d_in[12];
  const float* bv   = (const float*)d_in[13];
  const float* Wo   = (const float*)d_in[14];
  const float* bo   = (const float*)d_in[15];
  const float* ag   = (const float*)d_in[16];
  const float* ab   = (const float*)d_in[17];
  const float* W1   = (const float*)d_in[18];
  const float* b1   = (const float*)d_in[19];
  const float* W2   = (const float*)d_in[20];
  const float* b2   = (const float*)d_in[21];
  const float* fg   = (const float*)d_in[22];
  const float* fb   = (const float*)d_in[23];
  const float* sw   = (const float*)d_in[24];
  const float* sb   = (const float*)d_in[25];
  const float* ew   = (const float*)d_in[26];
  const float* ebd  = (const float*)d_in[27];
  const float* mw   = (const float*)d_in[28];
  const float* mb   = (const float*)d_in[29];
  float* out = (float*)d_out;

  // workspace layout (bytes)
  char* ws = (char*)d_ws;
  float* X      = (float*)(ws);                       // 12582912
  float* Y      = (float*)(ws + 12582912);            // 12582912
  float* SPROJ  = (float*)(ws + 25165824);            // 16384
  float* EPROJ  = (float*)(ws + 25182208);            // 16384
  float* BQKV   = (float*)(ws + 25198592);            // 36864
  unsigned short* XB    = (unsigned short*)(ws + 25235456);   // 6291456
  unsigned short* QKV   = (unsigned short*)(ws + 31526912);   // 18874368
  unsigned short* CTX   = (unsigned short*)(ws + 50401280);   // 6291456
  unsigned short* HBUF  = (unsigned short*)(ws + 56692736);   // 25165824
  unsigned short* WTALL = (unsigned short*)(ws + 81858560);   // 56623104
  // FF2 split-K partial reuses the (dead-by-then) QKV region
  float* Y2     = (float*)(ws + 31526912);            // 12582912, aliases QKV

  k_prep_weights<<<27648, dim3(32, 8), 0, stream>>>(Wq, Wk, Wv, Wo, W1, W2, WTALL);
  k_prep_bias<<<36, 256, 0, stream>>>(bq, bk, bv, BQKV);
  k_embed_ln<<<4096, 256, 0, stream>>>(ids, tts, we, pe, te, eg, ebv, X, XB);

  for (int l = 0; l < NL_; l++){
    unsigned short* wt = WTALL + (size_t)l * 7077888;
    k_gemm<1><<<dim3(18, 32, 1), 256, 0, stream>>>(XB, wt, BQKV + l * 2304, QKV, nullptr, 4096, 2304, 768, 768);
    k_attn_mfma<<<dim3(8, 12, 8), 256, 0, stream>>>(QKV, mask, CTX);
    k_gemm<0><<<dim3(6, 32, 1), 256, 0, stream>>>(CTX, wt + 1769472, bo + l * 768, Y, nullptr, 4096, 768, 768, 768);
    k_add_ln<<<4096, 256, 0, stream>>>(X, Y, nullptr, ag + l * 768, ab + l * 768, X, XB);
    k_gemm<2><<<dim3(24, 32, 1), 256, 0, stream>>>(XB, wt + 2359296, b1 + l * 3072, HBUF, nullptr, 4096, 3072, 768, 768);
    k_gemm<0><<<dim3(6, 32, 2), 256, 0, stream>>>(HBUF, wt + 4718592, b2 + l * 768, Y, Y2, 4096, 768, 3072, 1536);
    k_add_ln<<<4096, 256, 0, stream>>>(X, Y, Y2, fg + l * 768, fb + l * 768, X, XB);
  }

  k_heads<<<4096, 256, 0, stream>>>(X, sw, sb, ew, ebd, mw, out, SPROJ, EPROJ);
  k_match<<<2048, 256, 0, stream>>>(SPROJ, EPROJ, mb, out);
}

// Round 4
// 684.594 us; speedup vs baseline: 3.2526x; 1.1187x over previous
//
#include <hip/hip_runtime.h>

#define B_   8
#define L_   512
#define H_   768
#define NH_  12
#define DFF_ 3072
#define NL_  4
#define HD_  64
#define M_   4096

typedef __bf16 bf16x8 __attribute__((ext_vector_type(8)));
typedef float f32x4 __attribute__((ext_vector_type(4)));
typedef unsigned short u16x8 __attribute__((ext_vector_type(8)));

__device__ inline float bf2f(unsigned short u){
  union { unsigned int i; float f; } v; v.i = ((unsigned int)u) << 16; return v.f;
}
__device__ inline unsigned short f2bf(float f){
  union { float f; unsigned int i; } v; v.f = f;
  unsigned int x = v.i;
  return (unsigned short)((x + 0x7fffu + ((x >> 16) & 1u)) >> 16);
}

// ---------------- weight prep: transpose fp32 [R][C] -> bf16 [C][R] ----------------
__global__ void k_prep_weights(const float* __restrict__ Wq, const float* __restrict__ Wk,
                               const float* __restrict__ Wv, const float* __restrict__ Wo,
                               const float* __restrict__ W1, const float* __restrict__ W2,
                               unsigned short* __restrict__ wTall){
  __shared__ float tile[32][33];
  int id = blockIdx.x;
  int layer = id / 6912;
  int r = id % 6912;
  unsigned short* wt = wTall + (size_t)layer * 7077888;
  const float* src; unsigned short* dst; int R, C, tr;
  if (r < 2304){
    int mat = r / 576; tr = r % 576; R = 768; C = 768;
    const float* s;
    if (mat == 0) s = Wq; else if (mat == 1) s = Wk; else if (mat == 2) s = Wv; else s = Wo;
    src = s + (size_t)layer * 589824;
    dst = wt + (size_t)mat * 589824;
  } else if (r < 4608){
    tr = r - 2304; R = 768; C = 3072;
    src = W1 + (size_t)layer * 2359296; dst = wt + 2359296;
  } else {
    tr = r - 4608; R = 3072; C = 768;
    src = W2 + (size_t)layer * 2359296; dst = wt + 4718592;
  }
  int tilesC = C >> 5;
  int r0 = (tr / tilesC) << 5, c0 = (tr % tilesC) << 5;
  int tx = threadIdx.x, ty = threadIdx.y; // (32,8)
  #pragma unroll
  for (int i = 0; i < 32; i += 8)
    tile[ty + i][tx] = src[(size_t)(r0 + ty + i) * C + c0 + tx];
  __syncthreads();
  #pragma unroll
  for (int j = 0; j < 32; j += 8)
    dst[(size_t)(c0 + ty + j) * R + r0 + tx] = f2bf(tile[tx][ty + j]);
}

// concat qkv bias per layer: [NL][2304]
__global__ void k_prep_bias(const float* __restrict__ bq, const float* __restrict__ bk,
                            const float* __restrict__ bv, float* __restrict__ out){
  int i = blockIdx.x * 256 + threadIdx.x; // 4*2304
  int layer = i / 2304, c = i % 2304;
  float v;
  if (c < 768) v = bq[layer * 768 + c];
  else if (c < 1536) v = bk[layer * 768 + c - 768];
  else v = bv[layer * 768 + c - 1536];
  out[i] = v;
}

// ---------------- embedding + LN ----------------
__global__ __launch_bounds__(256) void k_embed_ln(const int* __restrict__ ids, const int* __restrict__ tts,
                           const float* __restrict__ we, const float* __restrict__ pe,
                           const float* __restrict__ te, const float* __restrict__ g,
                           const float* __restrict__ b, float* __restrict__ x,
                           unsigned short* __restrict__ xb){
  int row = blockIdx.x;           // 4096
  int l = row & 511;
  int id = ids[row], tt = tts[row];
  int t = threadIdx.x;            // 256
  float v[3]; float s = 0.f, s2 = 0.f;
  #pragma unroll
  for (int i = 0; i < 3; i++){
    int c = t + i * 256;
    float val = we[(size_t)id * 768 + c] + pe[(size_t)l * 768 + c] + te[(size_t)tt * 768 + c];
    v[i] = val; s += val; s2 += val * val;
  }
  #pragma unroll
  for (int o = 32; o > 0; o >>= 1){ s += __shfl_down(s, o); s2 += __shfl_down(s2, o); }
  __shared__ float red[2][4];
  int wv = t >> 6;
  if ((t & 63) == 0){ red[0][wv] = s; red[1][wv] = s2; }
  __syncthreads();
  s = red[0][0] + red[0][1] + red[0][2] + red[0][3];
  s2 = red[1][0] + red[1][1] + red[1][2] + red[1][3];
  float mean = s * (1.f / 768.f);
  float var = s2 * (1.f / 768.f) - mean * mean;
  float rstd = rsqrtf(var + 1e-12f);
  #pragma unroll
  for (int i = 0; i < 3; i++){
    int c = t + i * 256;
    float nv = (v[i] - mean) * rstd * g[c] + b[c];
    x[(size_t)row * 768 + c] = nv;
    xb[(size_t)row * 768 + c] = f2bf(nv);
  }
}

// ---------------- residual add (+ optional second partial) + LN ----------------
__global__ __launch_bounds__(256) void k_add_ln(const float* __restrict__ xin, const float* __restrict__ y,
                         const float* __restrict__ y2,
                         const float* __restrict__ g, const float* __restrict__ b,
                         float* __restrict__ x, unsigned short* __restrict__ xb){
  int row = blockIdx.x;
  int t = threadIdx.x;
  float v[3]; float s = 0.f, s2 = 0.f;
  #pragma unroll
  for (int i = 0; i < 3; i++){
    int c = t + i * 256;
    float val = xin[(size_t)row * 768 + c] + y[(size_t)row * 768 + c];
    if (y2) val += y2[(size_t)row * 768 + c];
    v[i] = val; s += val; s2 += val * val;
  }
  #pragma unroll
  for (int o = 32; o > 0; o >>= 1){ s += __shfl_down(s, o); s2 += __shfl_down(s2, o); }
  __shared__ float red[2][4];
  int wv = t >> 6;
  if ((t & 63) == 0){ red[0][wv] = s; red[1][wv] = s2; }
  __syncthreads();
  s = red[0][0] + red[0][1] + red[0][2] + red[0][3];
  s2 = red[1][0] + red[1][1] + red[1][2] + red[1][3];
  float mean = s * (1.f / 768.f);
  float var = s2 * (1.f / 768.f) - mean * mean;
  float rstd = rsqrtf(var + 1e-12f);
  #pragma unroll
  for (int i = 0; i < 3; i++){
    int c = t + i * 256;
    float nv = (v[i] - mean) * rstd * g[c] + b[c];
    x[(size_t)row * 768 + c] = nv;
    xb[(size_t)row * 768 + c] = f2bf(nv);
  }
}

// ---------------- bf16 MFMA GEMM, counted-vmcnt 2-deep pipeline + T2 swizzle ----------------
// C[M][N] = A[M][K(slice)] @ BT[N][K]^T + bias.  blockIdx.z selects K-slice; z>0 -> Cout2.
// MODE 0: f32 out; MODE 1: bf16 out; MODE 2: bf16 gelu(out)
// LDS layout is XOR-swizzled: 16B group g of row r stored at group g^(r&7).
// Staging achieves this for free by permuting the per-lane GLOBAL source column
// ((lane&7)^(lane>>3) — same 128B segments, zero coalescing cost); global_load_lds
// destination stays linear (HW requirement).
template<int MODE>
__global__ __launch_bounds__(256) void k_gemm(const unsigned short* __restrict__ A,
                                              const unsigned short* __restrict__ BT,
                                              const float* __restrict__ bias,
                                              void* __restrict__ Cout, void* __restrict__ Cout2,
                                              int M, int N, int K, int Ksub){
  __shared__ __attribute__((aligned(16))) unsigned short smem[2][2][8192]; // [buf][A|B][128*64]
  int tid = threadIdx.x;
  int lane = tid & 63, wave = tid >> 6;
  int lr = lane & 15, lg = lane >> 4;

  // XCD-aware swizzle of flat tile id (nwg % 8 == 0 in all launches)
  int gx = gridDim.x;
  int nwg = gx * gridDim.y;
  int flat = blockIdx.y * gx + blockIdx.x;
  int cpx = nwg >> 3;
  int swz = (flat & 7) * cpx + (flat >> 3);
  int bx = swz % gx, by = swz / gx;

  int bm0 = by * 128, bn0 = bx * 128;
  int wr = wave >> 1, wc = wave & 1;
  int kz = blockIdx.z * Ksub;

  f32x4 acc[4][4];
  #pragma unroll
  for (int m = 0; m < 4; m++)
    #pragma unroll
    for (int n = 0; n < 4; n++)
      acc[m][n] = (f32x4){0.f, 0.f, 0.f, 0.f};

  // per-lane pre-swizzled source column (T2, m173 pattern)
  int scol = (((lane & 7) ^ (lane >> 3)) << 3);
  const unsigned short* gaBase = A + (size_t)(bm0 + (lane >> 3)) * K + kz + scol;
  const unsigned short* gbBase = BT + (size_t)(bn0 + (lane >> 3)) * K + kz + scol;

  int nk = Ksub >> 6;

  auto STAGE = [&](int buf, int t){
    const unsigned short* gA = gaBase + (t << 6);
    const unsigned short* gB = gbBase + (t << 6);
    unsigned short* as = &smem[buf][0][0];
    unsigned short* bs = &smem[buf][1][0];
    #pragma unroll
    for (int i = 0; i < 4; i++){
      size_t ro = (size_t)((wave * 4 + i) * 8) * K;
      __builtin_amdgcn_global_load_lds(
        (const __attribute__((address_space(1))) void*)(gA + ro),
        (__attribute__((address_space(3))) void*)(as + (wave * 4 + i) * 512), 16, 0, 0);
      __builtin_amdgcn_global_load_lds(
        (const __attribute__((address_space(1))) void*)(gB + ro),
        (__attribute__((address_space(3))) void*)(bs + (wave * 4 + i) * 512), 16, 0, 0);
    }
  };

  auto COMPUTE = [&](int buf){
    const unsigned short* as = &smem[buf][0][0];
    const unsigned short* bs = &smem[buf][1][0];
    #pragma unroll
    for (int kk = 0; kk < 2; kk++){
      bf16x8 av[4], bv[4];
      #pragma unroll
      for (int m = 0; m < 4; m++)
        av[m] = *(const bf16x8*)(as + (wr * 64 + m * 16 + lr) * 64 + (((4 * kk + lg) ^ (lr & 7)) << 3));
      #pragma unroll
      for (int n = 0; n < 4; n++)
        bv[n] = *(const bf16x8*)(bs + (wc * 64 + n * 16 + lr) * 64 + (((4 * kk + lg) ^ (lr & 7)) << 3));
      #pragma unroll
      for (int m = 0; m < 4; m++)
        #pragma unroll
        for (int n = 0; n < 4; n++)
          acc[m][n] = __builtin_amdgcn_mfma_f32_16x16x32_bf16(av[m], bv[n], acc[m][n], 0, 0, 0);
    }
  };

  // prologue: 2 tiles in flight
  STAGE(0, 0);
  STAGE(1, 1);
  for (int t = 0; t < nk; t++){
    if (t < nk - 1){
      asm volatile("s_waitcnt vmcnt(8)" ::: "memory");   // own tile-t loads done; t+1 stays in flight
    } else {
      asm volatile("s_waitcnt vmcnt(0)" ::: "memory");   // tail drain
    }
    __builtin_amdgcn_sched_barrier(0);
    __builtin_amdgcn_s_barrier();                        // all waves' tile-t rows resident
    __builtin_amdgcn_sched_barrier(0);
    COMPUTE(t & 1);
    __builtin_amdgcn_sched_barrier(0);
    __builtin_amdgcn_s_barrier();                        // all waves done reading buf[t&1]
    __builtin_amdgcn_sched_barrier(0);
    if (t + 2 < nk) STAGE(t & 1, t + 2);
  }

  int r0 = wr * 64 + 4 * lg;
  int c0 = wc * 64 + lr;
  if (MODE == 0){
    float* cs = (float*)smem;
    #pragma unroll
    for (int n = 0; n < 4; n++){
      int c = c0 + 16 * n;
      float bsv = (blockIdx.z == 0) ? bias[bn0 + c] : 0.f;
      #pragma unroll
      for (int m = 0; m < 4; m++)
        #pragma unroll
        for (int j = 0; j < 4; j++)
          cs[(r0 + m * 16 + j) * 128 + c] = acc[m][n][j] + bsv;
    }
    __syncthreads();
    float* Cf = (float*)(blockIdx.z == 0 ? Cout : Cout2);
    #pragma unroll
    for (int p = 0; p < 16; p++){
      int idx = p * 1024 + tid * 4;
      int row = idx >> 7, col = idx & 127;
      f32x4 v = *(const f32x4*)(cs + idx);
      *(f32x4*)(Cf + (size_t)(bm0 + row) * N + bn0 + col) = v;
    }
  } else {
    unsigned short* cs = (unsigned short*)smem;
    #pragma unroll
    for (int n = 0; n < 4; n++){
      int c = c0 + 16 * n;
      float bsv = bias[bn0 + c];
      #pragma unroll
      for (int m = 0; m < 4; m++)
        #pragma unroll
        for (int j = 0; j < 4; j++){
          float v = acc[m][n][j] + bsv;
          if (MODE == 2) v = 0.5f * v * (1.f + erff(v * 0.70710678118f));
          cs[(r0 + m * 16 + j) * 128 + c] = f2bf(v);
        }
    }
    __syncthreads();
    unsigned short* Cb = (unsigned short*)Cout;
    #pragma unroll
    for (int p = 0; p < 8; p++){
      int idx = p * 2048 + tid * 8;
      int row = idx >> 7, col = idx & 127;
      u16x8 v = *(const u16x8*)(cs + idx);
      *(u16x8*)(Cb + (size_t)(bm0 + row) * N + bn0 + col) = v;
    }
  }
}

// ---------------- MFMA flash attention ----------------
__global__ __launch_bounds__(256) void k_attn_mfma(const unsigned short* __restrict__ qkv,
                                                   const int* __restrict__ mask,
                                                   unsigned short* __restrict__ ctx){
  int qt = blockIdx.x, h = blockIdx.y, b = blockIdx.z;
  int tid = threadIdx.x;
  int lane = tid & 63, w = tid >> 6;
  int lr = lane & 15, lg = lane >> 4;

  __shared__ __attribute__((aligned(16))) unsigned short Ks[64][72];
  __shared__ __attribute__((aligned(16))) unsigned short VsT[64][72];
  __shared__ __attribute__((aligned(16))) unsigned short Ps[4][16][72];
  __shared__ float biasS[64];

  int qrow = b * 512 + qt * 64 + w * 16 + lr;
  const unsigned short* qp = qkv + (size_t)qrow * 2304 + h * 64 + lg * 8;
  bf16x8 qa[2];
  qa[0] = *(const bf16x8*)(qp);
  qa[1] = *(const bf16x8*)(qp + 32);

  f32x4 oacc[4];
  #pragma unroll
  for (int dt = 0; dt < 4; dt++) oacc[dt] = (f32x4){0.f, 0.f, 0.f, 0.f};
  float mrow[4], lrow[4];
  #pragma unroll
  for (int j = 0; j < 4; j++){ mrow[j] = -1e30f; lrow[j] = 0.f; }

  for (int c = 0; c < 8; c++){
    __syncthreads();
    {
      int r = tid >> 2, d0 = (tid & 3) << 4;
      const unsigned short* kp = qkv + (size_t)(b * 512 + c * 64 + r) * 2304 + 768 + h * 64 + d0;
      u16x8 k0 = *(const u16x8*)kp;
      u16x8 k1 = *(const u16x8*)(kp + 8);
      *(u16x8*)(&Ks[r][d0]) = k0;
      *(u16x8*)(&Ks[r][d0 + 8]) = k1;
    }
    {
      int kv = tid & 63, d0 = (tid >> 6) << 4;
      const unsigned short* vp = qkv + (size_t)(b * 512 + c * 64 + kv) * 2304 + 1536 + h * 64 + d0;
      u16x8 v0 = *(const u16x8*)vp;
      u16x8 v1 = *(const u16x8*)(vp + 8);
      #pragma unroll
      for (int j2 = 0; j2 < 8; j2++){
        VsT[d0 + j2][kv] = (unsigned short)v0[j2];
        VsT[d0 + 8 + j2][kv] = (unsigned short)v1[j2];
      }
    }
    if (tid < 64) biasS[tid] = (1.f - (float)mask[b * 512 + c * 64 + tid]) * -1e9f;
    __syncthreads();

    f32x4 sacc[4];
    #pragma unroll
    for (int n = 0; n < 4; n++) sacc[n] = (f32x4){0.f, 0.f, 0.f, 0.f};
    #pragma unroll
    for (int kk = 0; kk < 2; kk++){
      bf16x8 kb[4];
      #pragma unroll
      for (int n = 0; n < 4; n++)
        kb[n] = *(const bf16x8*)(&Ks[lr + 16 * n][lg * 8 + 32 * kk]);
      #pragma unroll
      for (int n = 0; n < 4; n++)
        sacc[n] = __builtin_amdgcn_mfma_f32_16x16x32_bf16(qa[kk], kb[n], sacc[n], 0, 0, 0);
    }

    float pv[4][4];
    #pragma unroll
    for (int n = 0; n < 4; n++){
      float bsv = biasS[lr + 16 * n];
      #pragma unroll
      for (int j = 0; j < 4; j++) pv[n][j] = sacc[n][j] * 0.125f + bsv;
    }
    #pragma unroll
    for (int j = 0; j < 4; j++){
      float mx = fmaxf(fmaxf(pv[0][j], pv[1][j]), fmaxf(pv[2][j], pv[3][j]));
      mx = fmaxf(mx, __shfl_xor(mx, 1));
      mx = fmaxf(mx, __shfl_xor(mx, 2));
      mx = fmaxf(mx, __shfl_xor(mx, 4));
      mx = fmaxf(mx, __shfl_xor(mx, 8));
      float mnew = fmaxf(mrow[j], mx);
      float corr = __expf(mrow[j] - mnew);
      float ps = 0.f;
      #pragma unroll
      for (int n = 0; n < 4; n++){
        pv[n][j] = __expf(pv[n][j] - mnew);
        ps += pv[n][j];
      }
      ps += __shfl_xor(ps, 1);
      ps += __shfl_xor(ps, 2);
      ps += __shfl_xor(ps, 4);
      ps += __shfl_xor(ps, 8);
      lrow[j] = lrow[j] * corr + ps;
      mrow[j] = mnew;
      #pragma unroll
      for (int dt = 0; dt < 4; dt++) oacc[dt][j] *= corr;
    }

    #pragma unroll
    for (int n = 0; n < 4; n++)
      #pragma unroll
      for (int j = 0; j < 4; j++)
        Ps[w][4 * lg + j][lr + 16 * n] = f2bf(pv[n][j]);

    #pragma unroll
    for (int kk = 0; kk < 2; kk++){
      bf16x8 pa = *(const bf16x8*)(&Ps[w][lr][lg * 8 + 32 * kk]);
      bf16x8 vb[4];
      #pragma unroll
      for (int dt = 0; dt < 4; dt++)
        vb[dt] = *(const bf16x8*)(&VsT[lr + 16 * dt][lg * 8 + 32 * kk]);
      #pragma unroll
      for (int dt = 0; dt < 4; dt++)
        oacc[dt] = __builtin_amdgcn_mfma_f32_16x16x32_bf16(pa, vb[dt], oacc[dt], 0, 0, 0);
    }
  }

  #pragma unroll
  for (int j = 0; j < 4; j++){
    float inv = 1.f / lrow[j];
    int row = b * 512 + qt * 64 + w * 16 + 4 * lg + j;
    unsigned short* o = ctx + (size_t)row * 768 + h * 64;
    #pragma unroll
    for (int dt = 0; dt < 4; dt++)
      o[lr + 16 * dt] = f2bf(oacc[dt][j] * inv);
  }
}

// ---------------- span heads ----------------
__global__ __launch_bounds__(256) void k_heads(const float* __restrict__ x,
                        const float* __restrict__ sw, const float* __restrict__ sb,
                        const float* __restrict__ ew, const float* __restrict__ eb,
                        const float* __restrict__ mw,
                        float* __restrict__ out, float* __restrict__ sproj, float* __restrict__ eproj){
  int row = blockIdx.x;
  int t = threadIdx.x;
  float a0 = 0.f, a1 = 0.f, a2 = 0.f, a3 = 0.f;
  #pragma unroll
  for (int i = 0; i < 3; i++){
    int c = t + i * 256;
    float v = x[(size_t)row * 768 + c];
    a0 += v * sw[c]; a1 += v * ew[c]; a2 += v * mw[c]; a3 += v * mw[768 + c];
  }
  #pragma unroll
  for (int o = 32; o > 0; o >>= 1){
    a0 += __shfl_down(a0, o); a1 += __shfl_down(a1, o);
    a2 += __shfl_down(a2, o); a3 += __shfl_down(a3, o);
  }
  __shared__ float red[4][4];
  int wv = t >> 6;
  if ((t & 63) == 0){ red[0][wv] = a0; red[1][wv] = a1; red[2][wv] = a2; red[3][wv] = a3; }
  __syncthreads();
  if (t == 0){
    float s0 = red[0][0] + red[0][1] + red[0][2] + red[0][3];
    float s1 = red[1][0] + red[1][1] + red[1][2] + red[1][3];
    float s2 = red[2][0] + red[2][1] + red[2][2] + red[2][3];
    float s3 = red[3][0] + red[3][1] + red[3][2] + red[3][3];
    out[row] = s0 + sb[0];
    out[4096 + row] = s1 + eb[0];
    sproj[row] = s2;
    eproj[row] = s3;
  }
}

__global__ __launch_bounds__(256) void k_match(const float* __restrict__ sproj, const float* __restrict__ eproj,
                        const float* __restrict__ mb, float* __restrict__ out){
  int idx = blockIdx.x * 256 + threadIdx.x;
  int j4 = idx & 127;
  int rest = idx >> 7;
  float sp = sproj[rest] + mb[0];
  const float* ep = eproj + ((rest >> 9) << 9) + j4 * 4;
  float4 r;
  r.x = sp + ep[0]; r.y = sp + ep[1]; r.z = sp + ep[2]; r.w = sp + ep[3];
  ((float4*)(out + 8192))[idx] = r;
}

extern "C" void kernel_launch(void* const* d_in, const int* in_sizes, int n_in,
                              void* d_out, int out_size, void* d_ws, size_t ws_size,
                              hipStream_t stream){
  (void)in_sizes; (void)n_in; (void)out_size; (void)ws_size;
  const int*   ids  = (const int*)d_in[0];
  const int*   tts  = (const int*)d_in[1];
  const int*   mask = (const int*)d_in[2];
  const float* we   = (const float*)d_in[3];
  const float* pe   = (const float*)d_in[4];
  const float* te   = (const float*)d_in[5];
  const float* eg   = (const float*)d_in[6];
  const float* ebv  = (const float*)d_in[7];
  const float* Wq   = (const float*)d_in[8];
  const float* bq   = (const float*)d_in[9];
  const float* Wk   = (const float*)d_in[10];
  const float* bk   = (const float*)d_in[11];
  const float* Wv   = (const float*)d_in[12];
  const float* bv   = (const float*)d_in[13];
  const float* Wo   = (const float*)d_in[14];
  const float* bo   = (const float*)d_in[15];
  const float* ag   = (const float*)d_in[16];
  const float* ab   = (const float*)d_in[17];
  const float* W1   = (const float*)d_in[18];
  const float* b1   = (const float*)d_in[19];
  const float* W2   = (const float*)d_in[20];
  const float* b2   = (const float*)d_in[21];
  const float* fg   = (const float*)d_in[22];
  const float* fb   = (const float*)d_in[23];
  const float* sw   = (const float*)d_in[24];
  const float* sb   = (const float*)d_in[25];
  const float* ew   = (const float*)d_in[26];
  const float* ebd  = (const float*)d_in[27];
  const float* mw   = (const float*)d_in[28];
  const float* mb   = (const float*)d_in[29];
  float* out = (float*)d_out;

  // workspace layout (bytes)
  char* ws = (char*)d_ws;
  float* X      = (float*)(ws);                       // 12582912
  float* Y      = (float*)(ws + 12582912);            // 12582912
  float* SPROJ  = (float*)(ws + 25165824);            // 16384
  float* EPROJ  = (float*)(ws + 25182208);            // 16384
  float* BQKV   = (float*)(ws + 25198592);            // 36864
  unsigned short* XB    = (unsigned short*)(ws + 25235456);   // 6291456
  unsigned short* QKV   = (unsigned short*)(ws + 31526912);   // 18874368
  unsigned short* CTX   = (unsigned short*)(ws + 50401280);   // 6291456
  unsigned short* HBUF  = (unsigned short*)(ws + 56692736);   // 25165824
  unsigned short* WTALL = (unsigned short*)(ws + 81858560);   // 56623104
  // FF2 split-K partial reuses the (dead-by-then) QKV region
  float* Y2     = (float*)(ws + 31526912);            // 12582912, aliases QKV

  k_prep_weights<<<27648, dim3(32, 8), 0, stream>>>(Wq, Wk, Wv, Wo, W1, W2, WTALL);
  k_prep_bias<<<36, 256, 0, stream>>>(bq, bk, bv, BQKV);
  k_embed_ln<<<4096, 256, 0, stream>>>(ids, tts, we, pe, te, eg, ebv, X, XB);

  for (int l = 0; l < NL_; l++){
    unsigned short* wt = WTALL + (size_t)l * 7077888;
    k_gemm<1><<<dim3(18, 32, 1), 256, 0, stream>>>(XB, wt, BQKV + l * 2304, QKV, nullptr, 4096, 2304, 768, 768);
    k_attn_mfma<<<dim3(8, 12, 8), 256, 0, stream>>>(QKV, mask, CTX);
    k_gemm<0><<<dim3(6, 32, 1), 256, 0, stream>>>(CTX, wt + 1769472, bo + l * 768, Y, nullptr, 4096, 768, 768, 768);
    k_add_ln<<<4096, 256, 0, stream>>>(X, Y, nullptr, ag + l * 768, ab + l * 768, X, XB);
    k_gemm<2><<<dim3(24, 32, 1), 256, 0, stream>>>(XB, wt + 2359296, b1 + l * 3072, HBUF, nullptr, 4096, 3072, 768, 768);
    k_gemm<0><<<dim3(6, 32, 2), 256, 0, stream>>>(HBUF, wt + 4718592, b2 + l * 768, Y, Y2, 4096, 768, 3072, 1536);
    k_add_ln<<<4096, 256, 0, stream>>>(X, Y, Y2, fg + l * 768, fb + l * 768, X, XB);
  }

  k_heads<<<4096, 256, 0, stream>>>(X, sw, sb, ew, ebd, mw, out, SPROJ, EPROJ);
  k_match<<<2048, 256, 0, stream>>>(SPROJ, EPROJ, mb, out);
}

// Round 5
// 659.331 us; speedup vs baseline: 3.3772x; 1.0383x over previous
//
#include <hip/hip_runtime.h>

#define B_   8
#define L_   512
#define H_   768
#define NH_  12
#define DFF_ 3072
#define NL_  4
#define HD_  64
#define M_   4096

typedef __bf16 bf16x8 __attribute__((ext_vector_type(8)));
typedef float f32x4 __attribute__((ext_vector_type(4)));
typedef unsigned short u16x8 __attribute__((ext_vector_type(8)));

__device__ inline float bf2f(unsigned short u){
  union { unsigned int i; float f; } v; v.i = ((unsigned int)u) << 16; return v.f;
}
__device__ inline unsigned short f2bf(float f){
  union { float f; unsigned int i; } v; v.f = f;
  unsigned int x = v.i;
  return (unsigned short)((x + 0x7fffu + ((x >> 16) & 1u)) >> 16);
}

// ---------------- weight prep: transpose fp32 [R][C] -> bf16 [C][R] ----------------
__global__ void k_prep_weights(const float* __restrict__ Wq, const float* __restrict__ Wk,
                               const float* __restrict__ Wv, const float* __restrict__ Wo,
                               const float* __restrict__ W1, const float* __restrict__ W2,
                               unsigned short* __restrict__ wTall){
  __shared__ float tile[32][33];
  int id = blockIdx.x;
  int layer = id / 6912;
  int r = id % 6912;
  unsigned short* wt = wTall + (size_t)layer * 7077888;
  const float* src; unsigned short* dst; int R, C, tr;
  if (r < 2304){
    int mat = r / 576; tr = r % 576; R = 768; C = 768;
    const float* s;
    if (mat == 0) s = Wq; else if (mat == 1) s = Wk; else if (mat == 2) s = Wv; else s = Wo;
    src = s + (size_t)layer * 589824;
    dst = wt + (size_t)mat * 589824;
  } else if (r < 4608){
    tr = r - 2304; R = 768; C = 3072;
    src = W1 + (size_t)layer * 2359296; dst = wt + 2359296;
  } else {
    tr = r - 4608; R = 3072; C = 768;
    src = W2 + (size_t)layer * 2359296; dst = wt + 4718592;
  }
  int tilesC = C >> 5;
  int r0 = (tr / tilesC) << 5, c0 = (tr % tilesC) << 5;
  int tx = threadIdx.x, ty = threadIdx.y; // (32,8)
  #pragma unroll
  for (int i = 0; i < 32; i += 8)
    tile[ty + i][tx] = src[(size_t)(r0 + ty + i) * C + c0 + tx];
  __syncthreads();
  #pragma unroll
  for (int j = 0; j < 32; j += 8)
    dst[(size_t)(c0 + ty + j) * R + r0 + tx] = f2bf(tile[tx][ty + j]);
}

// concat qkv bias per layer: [NL][2304]
__global__ void k_prep_bias(const float* __restrict__ bq, const float* __restrict__ bk,
                            const float* __restrict__ bv, float* __restrict__ out){
  int i = blockIdx.x * 256 + threadIdx.x; // 4*2304
  int layer = i / 2304, c = i % 2304;
  float v;
  if (c < 768) v = bq[layer * 768 + c];
  else if (c < 1536) v = bk[layer * 768 + c - 768];
  else v = bv[layer * 768 + c - 1536];
  out[i] = v;
}

// ---------------- embedding + LN ----------------
__global__ __launch_bounds__(256) void k_embed_ln(const int* __restrict__ ids, const int* __restrict__ tts,
                           const float* __restrict__ we, const float* __restrict__ pe,
                           const float* __restrict__ te, const float* __restrict__ g,
                           const float* __restrict__ b, float* __restrict__ x,
                           unsigned short* __restrict__ xb){
  int row = blockIdx.x;           // 4096
  int l = row & 511;
  int id = ids[row], tt = tts[row];
  int t = threadIdx.x;            // 256
  float v[3]; float s = 0.f, s2 = 0.f;
  #pragma unroll
  for (int i = 0; i < 3; i++){
    int c = t + i * 256;
    float val = we[(size_t)id * 768 + c] + pe[(size_t)l * 768 + c] + te[(size_t)tt * 768 + c];
    v[i] = val; s += val; s2 += val * val;
  }
  #pragma unroll
  for (int o = 32; o > 0; o >>= 1){ s += __shfl_down(s, o); s2 += __shfl_down(s2, o); }
  __shared__ float red[2][4];
  int wv = t >> 6;
  if ((t & 63) == 0){ red[0][wv] = s; red[1][wv] = s2; }
  __syncthreads();
  s = red[0][0] + red[0][1] + red[0][2] + red[0][3];
  s2 = red[1][0] + red[1][1] + red[1][2] + red[1][3];
  float mean = s * (1.f / 768.f);
  float var = s2 * (1.f / 768.f) - mean * mean;
  float rstd = rsqrtf(var + 1e-12f);
  #pragma unroll
  for (int i = 0; i < 3; i++){
    int c = t + i * 256;
    float nv = (v[i] - mean) * rstd * g[c] + b[c];
    x[(size_t)row * 768 + c] = nv;
    xb[(size_t)row * 768 + c] = f2bf(nv);
  }
}

// ---------------- residual add (+ optional second bf16 partial) + LN ----------------
__global__ __launch_bounds__(256) void k_add_ln(const float* __restrict__ xin,
                         const unsigned short* __restrict__ y,
                         const unsigned short* __restrict__ y2,
                         const float* __restrict__ g, const float* __restrict__ b,
                         float* __restrict__ x, unsigned short* __restrict__ xb){
  int row = blockIdx.x;
  int t = threadIdx.x;
  float v[3]; float s = 0.f, s2 = 0.f;
  #pragma unroll
  for (int i = 0; i < 3; i++){
    int c = t + i * 256;
    float val = xin[(size_t)row * 768 + c] + bf2f(y[(size_t)row * 768 + c]);
    if (y2) val += bf2f(y2[(size_t)row * 768 + c]);
    v[i] = val; s += val; s2 += val * val;
  }
  #pragma unroll
  for (int o = 32; o > 0; o >>= 1){ s += __shfl_down(s, o); s2 += __shfl_down(s2, o); }
  __shared__ float red[2][4];
  int wv = t >> 6;
  if ((t & 63) == 0){ red[0][wv] = s; red[1][wv] = s2; }
  __syncthreads();
  s = red[0][0] + red[0][1] + red[0][2] + red[0][3];
  s2 = red[1][0] + red[1][1] + red[1][2] + red[1][3];
  float mean = s * (1.f / 768.f);
  float var = s2 * (1.f / 768.f) - mean * mean;
  float rstd = rsqrtf(var + 1e-12f);
  #pragma unroll
  for (int i = 0; i < 3; i++){
    int c = t + i * 256;
    float nv = (v[i] - mean) * rstd * g[c] + b[c];
    x[(size_t)row * 768 + c] = nv;
    xb[(size_t)row * 768 + c] = f2bf(nv);
  }
}

// ---------------- bf16 MFMA GEMM, m97 structure (single 32KB buffer) + T2 swizzle ----------------
// C[M][N] = A[M][K(slice)] @ BT[N][K]^T + bias, output bf16.
// blockIdx.z selects K-slice; z>0 -> Cout2, no bias.  ACT 0: none; 1: gelu.
// LDS XOR-swizzled via pre-swizzled global source column (free; read side XORs back).
// __launch_bounds__(256,3): keep regs <=170 so 3 waves/SIMD (12 waves/CU) fit — the
// cross-block overlap (m114) is what hides the per-K-step barrier drain.
template<int ACT>
__global__ __launch_bounds__(256, 3) void k_gemm(const unsigned short* __restrict__ A,
                                              const unsigned short* __restrict__ BT,
                                              const float* __restrict__ bias,
                                              unsigned short* __restrict__ Cout,
                                              unsigned short* __restrict__ Cout2,
                                              int M, int N, int K, int Ksub){
  __shared__ __attribute__((aligned(16))) unsigned short smem[16384]; // As | Bs, 32 KB
  unsigned short* As = smem;
  unsigned short* Bs = smem + 8192;
  int tid = threadIdx.x;
  int lane = tid & 63, wave = tid >> 6;
  int lr = lane & 15, lg = lane >> 4;

  // XCD-aware swizzle of flat tile id (nwg % 8 == 0 in all launches)
  int gx = gridDim.x;
  int nwg = gx * gridDim.y;
  int flat = blockIdx.y * gx + blockIdx.x;
  int cpx = nwg >> 3;
  int swz = (flat & 7) * cpx + (flat >> 3);
  int bx = swz % gx, by = swz / gx;

  int bm0 = by * 128, bn0 = bx * 128;
  int wr = wave >> 1, wc = wave & 1;
  int kz = blockIdx.z * Ksub;

  f32x4 acc[4][4];
  #pragma unroll
  for (int m = 0; m < 4; m++)
    #pragma unroll
    for (int n = 0; n < 4; n++)
      acc[m][n] = (f32x4){0.f, 0.f, 0.f, 0.f};

  // per-lane pre-swizzled source column (T2, m173 pattern)
  int scol = (((lane & 7) ^ (lane >> 3)) << 3);
  const unsigned short* gaBase = A + (size_t)(bm0 + (lane >> 3)) * K + kz + scol;
  const unsigned short* gbBase = BT + (size_t)(bn0 + (lane >> 3)) * K + kz + scol;

  int nk = Ksub >> 6;
  for (int t = 0; t < nk; t++){
    if (t) __syncthreads();           // all waves done reading previous tile
    const unsigned short* gA = gaBase + (t << 6);
    const unsigned short* gB = gbBase + (t << 6);
    #pragma unroll
    for (int i = 0; i < 4; i++){
      size_t ro = (size_t)((wave * 4 + i) * 8) * K;
      __builtin_amdgcn_global_load_lds(
        (const __attribute__((address_space(1))) void*)(gA + ro),
        (__attribute__((address_space(3))) void*)(As + (wave * 4 + i) * 512), 16, 0, 0);
      __builtin_amdgcn_global_load_lds(
        (const __attribute__((address_space(1))) void*)(gB + ro),
        (__attribute__((address_space(3))) void*)(Bs + (wave * 4 + i) * 512), 16, 0, 0);
    }
    __syncthreads();                  // vmcnt(0)+barrier: tile resident
    #pragma unroll
    for (int kk = 0; kk < 2; kk++){
      bf16x8 av[4], bv[4];
      #pragma unroll
      for (int m = 0; m < 4; m++)
        av[m] = *(const bf16x8*)(As + (wr * 64 + m * 16 + lr) * 64 + (((4 * kk + lg) ^ (lr & 7)) << 3));
      #pragma unroll
      for (int n = 0; n < 4; n++)
        bv[n] = *(const bf16x8*)(Bs + (wc * 64 + n * 16 + lr) * 64 + (((4 * kk + lg) ^ (lr & 7)) << 3));
      #pragma unroll
      for (int m = 0; m < 4; m++)
        #pragma unroll
        for (int n = 0; n < 4; n++)
          acc[m][n] = __builtin_amdgcn_mfma_f32_16x16x32_bf16(av[m], bv[n], acc[m][n], 0, 0, 0);
    }
  }
  __syncthreads();                    // safe to reuse smem for epilogue

  // epilogue: stage bf16 C tile [128][128] in LDS, then linear coalesced stores
  int r0 = wr * 64 + 4 * lg;
  int c0 = wc * 64 + lr;
  unsigned short* cs = smem;
  bool z0 = (blockIdx.z == 0);
  #pragma unroll
  for (int n = 0; n < 4; n++){
    int c = c0 + 16 * n;
    float bsv = z0 ? bias[bn0 + c] : 0.f;
    #pragma unroll
    for (int m = 0; m < 4; m++)
      #pragma unroll
      for (int j = 0; j < 4; j++){
        float v = acc[m][n][j] + bsv;
        if (ACT == 1) v = 0.5f * v * (1.f + erff(v * 0.70710678118f));
        cs[(r0 + m * 16 + j) * 128 + c] = f2bf(v);
      }
  }
  __syncthreads();
  unsigned short* Cb = z0 ? Cout : Cout2;
  #pragma unroll
  for (int p = 0; p < 8; p++){
    int idx = p * 2048 + tid * 8;
    int row = idx >> 7, col = idx & 127;
    u16x8 v = *(const u16x8*)(cs + idx);
    *(u16x8*)(Cb + (size_t)(bm0 + row) * N + bn0 + col) = v;
  }
}

// ---------------- MFMA flash attention ----------------
__global__ __launch_bounds__(256) void k_attn_mfma(const unsigned short* __restrict__ qkv,
                                                   const int* __restrict__ mask,
                                                   unsigned short* __restrict__ ctx){
  int qt = blockIdx.x, h = blockIdx.y, b = blockIdx.z;
  int tid = threadIdx.x;
  int lane = tid & 63, w = tid >> 6;
  int lr = lane & 15, lg = lane >> 4;

  __shared__ __attribute__((aligned(16))) unsigned short Ks[64][72];
  __shared__ __attribute__((aligned(16))) unsigned short VsT[64][72];
  __shared__ __attribute__((aligned(16))) unsigned short Ps[4][16][72];
  __shared__ float biasS[64];

  int qrow = b * 512 + qt * 64 + w * 16 + lr;
  const unsigned short* qp = qkv + (size_t)qrow * 2304 + h * 64 + lg * 8;
  bf16x8 qa[2];
  qa[0] = *(const bf16x8*)(qp);
  qa[1] = *(const bf16x8*)(qp + 32);

  f32x4 oacc[4];
  #pragma unroll
  for (int dt = 0; dt < 4; dt++) oacc[dt] = (f32x4){0.f, 0.f, 0.f, 0.f};
  float mrow[4], lrow[4];
  #pragma unroll
  for (int j = 0; j < 4; j++){ mrow[j] = -1e30f; lrow[j] = 0.f; }

  for (int c = 0; c < 8; c++){
    __syncthreads();
    {
      int r = tid >> 2, d0 = (tid & 3) << 4;
      const unsigned short* kp = qkv + (size_t)(b * 512 + c * 64 + r) * 2304 + 768 + h * 64 + d0;
      u16x8 k0 = *(const u16x8*)kp;
      u16x8 k1 = *(const u16x8*)(kp + 8);
      *(u16x8*)(&Ks[r][d0]) = k0;
      *(u16x8*)(&Ks[r][d0 + 8]) = k1;
    }
    {
      int kv = tid & 63, d0 = (tid >> 6) << 4;
      const unsigned short* vp = qkv + (size_t)(b * 512 + c * 64 + kv) * 2304 + 1536 + h * 64 + d0;
      u16x8 v0 = *(const u16x8*)vp;
      u16x8 v1 = *(const u16x8*)(vp + 8);
      #pragma unroll
      for (int j2 = 0; j2 < 8; j2++){
        VsT[d0 + j2][kv] = (unsigned short)v0[j2];
        VsT[d0 + 8 + j2][kv] = (unsigned short)v1[j2];
      }
    }
    if (tid < 64) biasS[tid] = (1.f - (float)mask[b * 512 + c * 64 + tid]) * -1e9f;
    __syncthreads();

    f32x4 sacc[4];
    #pragma unroll
    for (int n = 0; n < 4; n++) sacc[n] = (f32x4){0.f, 0.f, 0.f, 0.f};
    #pragma unroll
    for (int kk = 0; kk < 2; kk++){
      bf16x8 kb[4];
      #pragma unroll
      for (int n = 0; n < 4; n++)
        kb[n] = *(const bf16x8*)(&Ks[lr + 16 * n][lg * 8 + 32 * kk]);
      #pragma unroll
      for (int n = 0; n < 4; n++)
        sacc[n] = __builtin_amdgcn_mfma_f32_16x16x32_bf16(qa[kk], kb[n], sacc[n], 0, 0, 0);
    }

    float pv[4][4];
    #pragma unroll
    for (int n = 0; n < 4; n++){
      float bsv = biasS[lr + 16 * n];
      #pragma unroll
      for (int j = 0; j < 4; j++) pv[n][j] = sacc[n][j] * 0.125f + bsv;
    }
    #pragma unroll
    for (int j = 0; j < 4; j++){
      float mx = fmaxf(fmaxf(pv[0][j], pv[1][j]), fmaxf(pv[2][j], pv[3][j]));
      mx = fmaxf(mx, __shfl_xor(mx, 1));
      mx = fmaxf(mx, __shfl_xor(mx, 2));
      mx = fmaxf(mx, __shfl_xor(mx, 4));
      mx = fmaxf(mx, __shfl_xor(mx, 8));
      float mnew = fmaxf(mrow[j], mx);
      float corr = __expf(mrow[j] - mnew);
      float ps = 0.f;
      #pragma unroll
      for (int n = 0; n < 4; n++){
        pv[n][j] = __expf(pv[n][j] - mnew);
        ps += pv[n][j];
      }
      ps += __shfl_xor(ps, 1);
      ps += __shfl_xor(ps, 2);
      ps += __shfl_xor(ps, 4);
      ps += __shfl_xor(ps, 8);
      lrow[j] = lrow[j] * corr + ps;
      mrow[j] = mnew;
      #pragma unroll
      for (int dt = 0; dt < 4; dt++) oacc[dt][j] *= corr;
    }

    #pragma unroll
    for (int n = 0; n < 4; n++)
      #pragma unroll
      for (int j = 0; j < 4; j++)
        Ps[w][4 * lg + j][lr + 16 * n] = f2bf(pv[n][j]);

    #pragma unroll
    for (int kk = 0; kk < 2; kk++){
      bf16x8 pa = *(const bf16x8*)(&Ps[w][lr][lg * 8 + 32 * kk]);
      bf16x8 vb[4];
      #pragma unroll
      for (int dt = 0; dt < 4; dt++)
        vb[dt] = *(const bf16x8*)(&VsT[lr + 16 * dt][lg * 8 + 32 * kk]);
      #pragma unroll
      for (int dt = 0; dt < 4; dt++)
        oacc[dt] = __builtin_amdgcn_mfma_f32_16x16x32_bf16(pa, vb[dt], oacc[dt], 0, 0, 0);
    }
  }

  #pragma unroll
  for (int j = 0; j < 4; j++){
    float inv = 1.f / lrow[j];
    int row = b * 512 + qt * 64 + w * 16 + 4 * lg + j;
    unsigned short* o = ctx + (size_t)row * 768 + h * 64;
    #pragma unroll
    for (int dt = 0; dt < 4; dt++)
      o[lr + 16 * dt] = f2bf(oacc[dt][j] * inv);
  }
}

// ---------------- span heads ----------------
__global__ __launch_bounds__(256) void k_heads(const float* __restrict__ x,
                        const float* __restrict__ sw, const float* __restrict__ sb,
                        const float* __restrict__ ew, const float* __restrict__ eb,
                        const float* __restrict__ mw,
                        float* __restrict__ out, float* __restrict__ sproj, float* __restrict__ eproj){
  int row = blockIdx.x;
  int t = threadIdx.x;
  float a0 = 0.f, a1 = 0.f, a2 = 0.f, a3 = 0.f;
  #pragma unroll
  for (int i = 0; i < 3; i++){
    int c = t + i * 256;
    float v = x[(size_t)row * 768 + c];
    a0 += v * sw[c]; a1 += v * ew[c]; a2 += v * mw[c]; a3 += v * mw[768 + c];
  }
  #pragma unroll
  for (int o = 32; o > 0; o >>= 1){
    a0 += __shfl_down(a0, o); a1 += __shfl_down(a1, o);
    a2 += __shfl_down(a2, o); a3 += __shfl_down(a3, o);
  }
  __shared__ float red[4][4];
  int wv = t >> 6;
  if ((t & 63) == 0){ red[0][wv] = a0; red[1][wv] = a1; red[2][wv] = a2; red[3][wv] = a3; }
  __syncthreads();
  if (t == 0){
    float s0 = red[0][0] + red[0][1] + red[0][2] + red[0][3];
    float s1 = red[1][0] + red[1][1] + red[1][2] + red[1][3];
    float s2 = red[2][0] + red[2][1] + red[2][2] + red[2][3];
    float s3 = red[3][0] + red[3][1] + red[3][2] + red[3][3];
    out[row] = s0 + sb[0];
    out[4096 + row] = s1 + eb[0];
    sproj[row] = s2;
    eproj[row] = s3;
  }
}

__global__ __launch_bounds__(256) void k_match(const float* __restrict__ sproj, const float* __restrict__ eproj,
                        const float* __restrict__ mb, float* __restrict__ out){
  int idx = blockIdx.x * 256 + threadIdx.x;
  int j4 = idx & 127;
  int rest = idx >> 7;
  float sp = sproj[rest] + mb[0];
  const float* ep = eproj + ((rest >> 9) << 9) + j4 * 4;
  float4 r;
  r.x = sp + ep[0]; r.y = sp + ep[1]; r.z = sp + ep[2]; r.w = sp + ep[3];
  ((float4*)(out + 8192))[idx] = r;
}

extern "C" void kernel_launch(void* const* d_in, const int* in_sizes, int n_in,
                              void* d_out, int out_size, void* d_ws, size_t ws_size,
                              hipStream_t stream){
  (void)in_sizes; (void)n_in; (void)out_size; (void)ws_size;
  const int*   ids  = (const int*)d_in[0];
  const int*   tts  = (const int*)d_in[1];
  const int*   mask = (const int*)d_in[2];
  const float* we   = (const float*)d_in[3];
  const float* pe   = (const float*)d_in[4];
  const float* te   = (const float*)d_in[5];
  const float* eg   = (const float*)d_in[6];
  const float* ebv  = (const float*)d_in[7];
  const float* Wq   = (const float*)d_in[8];
  const float* bq   = (const float*)d_in[9];
  const float* Wk   = (const float*)d_in[10];
  const float* bk   = (const float*)d_in[11];
  const float* Wv   = (const float*)d_in[12];
  const float* bv   = (const float*)d_in[13];
  const float* Wo   = (const float*)d_in[14];
  const float* bo   = (const float*)d_in[15];
  const float* ag   = (const float*)d_in[16];
  const float* ab   = (const float*)d_in[17];
  const float* W1   = (const float*)d_in[18];
  const float* b1   = (const float*)d_in[19];
  const float* W2   = (const float*)d_in[20];
  const float* b2   = (const float*)d_in[21];
  const float* fg   = (const float*)d_in[22];
  const float* fb   = (const float*)d_in[23];
  const float* sw   = (const float*)d_in[24];
  const float* sb   = (const float*)d_in[25];
  const float* ew   = (const float*)d_in[26];
  const float* ebd  = (const float*)d_in[27];
  const float* mw   = (const float*)d_in[28];
  const float* mb   = (const float*)d_in[29];
  float* out = (float*)d_out;

  // workspace layout (bytes)
  char* ws = (char*)d_ws;
  float* X      = (float*)(ws);                       // 12582912
  unsigned short* Y = (unsigned short*)(ws + 12582912);       // 6291456 (bf16 now)
  float* SPROJ  = (float*)(ws + 25165824);            // 16384
  float* EPROJ  = (float*)(ws + 25182208);            // 16384
  float* BQKV   = (float*)(ws + 25198592);            // 36864
  unsigned short* XB    = (unsigned short*)(ws + 25235456);   // 6291456
  unsigned short* QKV   = (unsigned short*)(ws + 31526912);   // 18874368
  unsigned short* CTX   = (unsigned short*)(ws + 50401280);   // 6291456
  unsigned short* HBUF  = (unsigned short*)(ws + 56692736);   // 25165824
  unsigned short* WTALL = (unsigned short*)(ws + 81858560);   // 56623104
  // FF2 split-K partial reuses the (dead-by-then) QKV region
  unsigned short* Y2    = (unsigned short*)(ws + 31526912);   // bf16, aliases QKV

  k_prep_weights<<<27648, dim3(32, 8), 0, stream>>>(Wq, Wk, Wv, Wo, W1, W2, WTALL);
  k_prep_bias<<<36, 256, 0, stream>>>(bq, bk, bv, BQKV);
  k_embed_ln<<<4096, 256, 0, stream>>>(ids, tts, we, pe, te, eg, ebv, X, XB);

  for (int l = 0; l < NL_; l++){
    unsigned short* wt = WTALL + (size_t)l * 7077888;
    k_gemm<0><<<dim3(18, 32, 1), 256, 0, stream>>>(XB, wt, BQKV + l * 2304, QKV, nullptr, 4096, 2304, 768, 768);
    k_attn_mfma<<<dim3(8, 12, 8), 256, 0, stream>>>(QKV, mask, CTX);
    k_gemm<0><<<dim3(6, 32, 1), 256, 0, stream>>>(CTX, wt + 1769472, bo + l * 768, Y, nullptr, 4096, 768, 768, 768);
    k_add_ln<<<4096, 256, 0, stream>>>(X, Y, nullptr, ag + l * 768, ab + l * 768, X, XB);
    k_gemm<1><<<dim3(24, 32, 1), 256, 0, stream>>>(XB, wt + 2359296, b1 + l * 3072, HBUF, nullptr, 4096, 3072, 768, 768);
    k_gemm<0><<<dim3(6, 32, 2), 256, 0, stream>>>(HBUF, wt + 4718592, b2 + l * 768, Y, Y2, 4096, 768, 3072, 1536);
    k_add_ln<<<4096, 256, 0, stream>>>(X, Y, Y2, fg + l * 768, fb + l * 768, X, XB);
  }

  k_heads<<<4096, 256, 0, stream>>>(X, sw, sb, ew, ebd, mw, out, SPROJ, EPROJ);
  k_match<<<2048, 256, 0, stream>>>(SPROJ, EPROJ, mb, out);
}